// Round 7
// baseline (356.480 us; speedup 1.0000x reference)
//
#include <hip/hip_runtime.h>
#include <math.h>

#define PRIME_Y 2654435761u

struct LevelParams { float scale; unsigned res; unsigned size; unsigned offset; };
struct EncParams { LevelParams lv[16]; };

typedef __attribute__((ext_vector_type(8))) short short8;
typedef __attribute__((ext_vector_type(4))) float f32x4;

struct alignas(8) F2 { float x, y; };

// fp32 pair -> packed bf16 (RNE), low = a, high = b.
__device__ inline unsigned bf2pack(float a, float b) {
  unsigned r;
  asm("v_cvt_pk_bf16_f32 %0, %1, %2" : "=v"(r) : "v"(a), "v"(b));
  return r;
}
__device__ inline F2 bf2unpack(unsigned u) {
  F2 r;
  r.x = __uint_as_float(u << 16);
  r.y = __uint_as_float(u & 0xFFFF0000u);
  return r;
}

// Fallback: full table fp32 [n][2] -> packed bf16 [n]
__global__ __launch_bounds__(256) void cvt_table(const F2* __restrict__ in,
                                                 unsigned* __restrict__ outb,
                                                 int n) {
  int i = blockIdx.x * 256 + threadIdx.x;
  if (i < n) {
    F2 v = in[i];
    outb[i] = bf2pack(v.x, v.y);
  }
}

// Prep. Dense [0,denseTotal): quad[v] = packed-bf16
// (T[v], T[(v+1)%sz], T[(v+res)%sz], T[(v+res+1)%sz]) -- one 16B load serves a
// full bilinear cell, wraps folded at build (exact reference semantics).
// Hashed [denseTotal,total): packed bf16 (4B), stored at hp[i-denseTotal].
__global__ __launch_bounds__(256) void prep3(
    const F2* __restrict__ in, uint4* __restrict__ quad,
    unsigned* __restrict__ hp, EncParams P, unsigned denseTotal,
    unsigned total) {
  unsigned i = blockIdx.x * 256 + threadIdx.x;
  if (i >= total) return;
  if (i >= denseTotal) {
    F2 a = in[i];
    hp[i - denseTotal] = bf2pack(a.x, a.y);
    return;
  }
  unsigned off = 0, size = 0, res = 0;
  #pragma unroll
  for (int l = 0; l < 12; ++l)
    if (i >= P.lv[l].offset) {
      off = P.lv[l].offset; size = P.lv[l].size; res = P.lv[l].res;
    }
  unsigned j = i - off;
  unsigned j1 = j + 1u;        if (j1 >= size) j1 -= size;
  unsigned j2 = j + res;       if (j2 >= size) j2 -= size;
  unsigned j3 = j + res + 1u;  if (j3 >= size) j3 -= size;
  F2 a0 = in[off + j],  a1 = in[off + j1];
  F2 a2 = in[off + j2], a3 = in[off + j3];
  quad[i] = make_uint4(bf2pack(a0.x, a0.y), bf2pack(a1.x, a1.y),
                       bf2pack(a2.x, a2.y), bf2pack(a3.x, a3.y));
}

// Primary-kernel LDS map (bytes):
//   [0,5120)     sW0  bf16 [64 rows][32] row stride 80
//   [5120,7168)  sW1  bf16 [16 rows][64] stride 128, XOR-swizzled (row&7)<<4
//   [7168,27648) per-wave region, 5120 B each:
//                  F bf16 [64][32] stride 80 (consumed into regs), then
//                  reluH HALF [64 m][32 j] stride 64, swz ^((m&3)<<4)
// 27648 -> LDS cap 5 blocks/CU.
// R6 lesson: (256,5) forced the ~120-reg demand (56 arch + 64 AGPR fw[4][16])
// under a 102 budget -> fw spilled to scratch (+560MB HBM, WRITE_SIZE 10x).
// R7: corner-half split shrinks the encode->MLP bridge to fw2[2][16]=32 regs
// (demand ~98); launch_bounds(256,4) = no-spill guarantee, occupancy rides
// the LDS cap to 5 blocks if the allocator lands <=102.
#define SMEM_BYTES 27648
#define SMEM_FB 39936   // fallback kernels keep the old map

// ============================================================================
// Primary kernel: 1 thread = 1 point, processed as two corner-halves sharing
// a y-row: half 0 = (cx0,cy0),(cx1,cy0); half 1 = (cx0,cy1),(cx1,cy1).
// Each half: encode 2 corners (hashed 2x3 union + dense quads) -> 2 MFMA
// rounds -> registers released before the next half encodes.
// ============================================================================
__global__ __launch_bounds__(256, 4) void plane_fwd1(
    const F2* __restrict__ xy,
    const uint4* __restrict__ qtab,     // dense quads, absolute entry index
    const unsigned* __restrict__ hp,    // hashed packed, base = denseTotal
    const float* __restrict__ w0g,
    const float* __restrict__ w1g,
    const int* __restrict__ boundp,
    float* __restrict__ out,
    EncParams P)
{
  __shared__ __align__(16) char smem[SMEM_BYTES];
  const int t = threadIdx.x;
  const int L = t & 63;
  const int w = t >> 6;
  const int r16 = L & 15;
  const int g = L >> 4;

  // ---- stage W0 (bf16, stride 80) ----
  {
    const float4* s = (const float4*)w0g;
    float4 a = s[t * 2], b = s[t * 2 + 1];
    uint4 pk = make_uint4(bf2pack(a.x, a.y), bf2pack(a.z, a.w),
                          bf2pack(b.x, b.y), bf2pack(b.z, b.w));
    *(uint4*)(smem + (t >> 2) * 80 + (t & 3) * 16) = pk;
  }
  // ---- stage W1 (bf16, [16][64] stride 128 swizzled, rows 8..15 = 0) ----
  {
    int row = t >> 4;
    int colb = (t & 15) * 8;
    float c0 = 0.f, c1 = 0.f, c2 = 0.f, c3 = 0.f;
    if (row < 8) {
      float4 wv = *(const float4*)(w1g + row * 64 + (t & 15) * 4);
      c0 = wv.x; c1 = wv.y; c2 = wv.z; c3 = wv.w;
    }
    *(uint2*)(smem + 5120 + row * 128 + (colb ^ ((row & 7) << 4))) =
        make_uint2(bf2pack(c0, c1), bf2pack(c2, c3));
  }

  char* sFH = smem + 7168 + w * 5120;

  // ---- per-point setup ----
  const int pt0 = blockIdx.x * 256 + t;
  F2 pxy = xy[pt0];

  int braw = boundp[0];
  float bf = (braw > 0x00800000) ? __int_as_float(braw) : (float)braw;
  float inv2b = 0.5f / bf;
  float xn = (pxy.x + bf) * inv2b;
  float yn = (pxy.y + bf) * inv2b;

  float cx  = fminf(fmaxf(xn * 2048.0f - 0.5f, 0.0f), 2047.0f);
  float cyv = fminf(fmaxf(yn * 2048.0f - 0.5f, 0.0f), 2047.0f);
  float cx0 = floorf(cx), cy0 = floorf(cyv);
  float u = cx - cx0, v = cyv - cy0;
  float cx1 = fminf(cx0 + 1.0f, 2047.0f);
  float cy1 = fminf(cy0 + 1.0f, 2047.0f);

  const float K = 1.0f / 2048.0f;
  const float gxc0 = (cx0 + 0.5f) * K, gxc1 = (cx1 + 0.5f) * K;
  const float gyc0 = (cy0 + 0.5f) * K, gyc1 = (cy1 + 0.5f) * K;

  const unsigned denseOff = P.lv[12].offset;

  f32x4 outacc[4];
  #pragma unroll
  for (int b = 0; b < 4; ++b) outacc[b] = (f32x4){0.f, 0.f, 0.f, 0.f};

  #pragma unroll
  for (int half = 0; half < 2; ++half) {
    const float gy = half ? gyc1 : gyc0;
    unsigned fw2[2][16];   // [corner-in-half][level], all indices static

    // ---- hashed levels 12..15 (2 rows x up-to-3 cols union) ----
    #pragma unroll
    for (int li = 0; li < 4; ++li) {
      const int l = 12 + li;
      const float scale   = P.lv[l].scale;
      const unsigned size = P.lv[l].size;
      const unsigned off  = P.lv[l].offset;
      const unsigned m = size - 1u;          // size == 2^19
      const unsigned* tb = hp + (off - denseOff);

      float px0 = fmaf(gxc0, scale, 0.5f), px1 = fmaf(gxc1, scale, 0.5f);
      float py  = fmaf(gy,   scale, 0.5f);
      float fx0 = floorf(px0), fx1 = floorf(px1), fyv = floorf(py);
      unsigned ux0 = (unsigned)fx0, ux1 = (unsigned)fx1;
      unsigned uy  = (unsigned)fyv;
      bool xs = (ux1 != ux0);                // delta <= 1 grid unit

      unsigned hya = uy * PRIME_Y;
      unsigned hyb = hya + PRIME_Y;

      unsigned h00 = tb[(ux0 ^ hya) & m];
      unsigned h10 = tb[((ux0 + 1u) ^ hya) & m];
      unsigned h01 = tb[(ux0 ^ hyb) & m];
      unsigned h11 = tb[((ux0 + 1u) ^ hyb) & m];
      unsigned h20 = 0u, h21 = 0u;
      if (xs) { h20 = tb[((ux0 + 2u) ^ hya) & m];
                h21 = tb[((ux0 + 2u) ^ hyb) & m]; }

      float frx0 = px0 - fx0, frx1 = px1 - fx1;
      float fry = py - fyv;

      #pragma unroll
      for (int c = 0; c < 2; ++c) {
        bool sx = (c != 0) && xs;
        unsigned e00 = sx ? h10 : h00;
        unsigned e10 = sx ? h20 : h10;
        unsigned e01 = sx ? h11 : h01;
        unsigned e11 = sx ? h21 : h11;
        float frx = c ? frx1 : frx0;
        F2 t00 = bf2unpack(e00), t10 = bf2unpack(e10);
        F2 t01 = bf2unpack(e01), t11 = bf2unpack(e11);
        float wx0 = 1.0f - frx, wx1 = frx;
        float wy0 = 1.0f - fry, wy1 = fry;
        float w00 = wx0 * wy0, w01 = wx0 * wy1;
        float w10 = wx1 * wy0, w11 = wx1 * wy1;
        float fx = w00 * t00.x + w01 * t01.x + w10 * t10.x + w11 * t11.x;
        float fy = w00 * t00.y + w01 * t01.y + w10 * t10.y + w11 * t11.y;
        fw2[c][l] = bf2pack(fx, fy);
      }
    }

    // ---- dense levels 0..11: quad = full bilinear cell per corner ----
    #pragma unroll
    for (int l = 0; l < 12; ++l) {
      const float scale   = P.lv[l].scale;
      const unsigned res  = P.lv[l].res;
      const unsigned off  = P.lv[l].offset;
      const uint4* qt = qtab + off;

      float px0 = fmaf(gxc0, scale, 0.5f), px1 = fmaf(gxc1, scale, 0.5f);
      float py  = fmaf(gy,   scale, 0.5f);
      float fx0 = floorf(px0), fx1 = floorf(px1), fyv = floorf(py);
      unsigned ux0 = (unsigned)fx0, ux1 = (unsigned)fx1;
      unsigned uy  = (unsigned)fyv;
      bool xs = (ux1 != ux0);

      unsigned vA = ux0 + uy * res;        // < size always
      uint4 qA = qt[vA];
      uint4 qB = make_uint4(0u, 0u, 0u, 0u);
      if (xs) qB = qt[vA + 1u];

      float frx0 = px0 - fx0, frx1 = px1 - fx1;
      float fry = py - fyv;

      #pragma unroll
      for (int c = 0; c < 2; ++c) {
        bool sx = (c != 0) && xs;
        unsigned qx = sx ? qB.x : qA.x;
        unsigned qy = sx ? qB.y : qA.y;
        unsigned qz = sx ? qB.z : qA.z;
        unsigned qw = sx ? qB.w : qA.w;
        float frx = c ? frx1 : frx0;
        F2 t00 = bf2unpack(qx), t10 = bf2unpack(qy);
        F2 t01 = bf2unpack(qz), t11 = bf2unpack(qw);
        float wx0 = 1.0f - frx, wx1 = frx;
        float wy0 = 1.0f - fry, wy1 = fry;
        float w00 = wx0 * wy0, w01 = wx0 * wy1;
        float w10 = wx1 * wy0, w11 = wx1 * wy1;
        float fx = w00 * t00.x + w01 * t01.x + w10 * t10.x + w11 * t11.x;
        float fy = w00 * t00.y + w01 * t01.y + w10 * t10.y + w11 * t11.y;
        fw2[c][l] = bf2pack(fx, fy);
      }
    }

    if (half == 0) __syncthreads();   // W0/W1 staged before first MFMA use

    // ---- 2 MFMA rounds for this half (round r = 2*half + rr) ----
    #pragma unroll
    for (int rr = 0; rr < 2; ++rr) {
      const int r = 2 * half + rr;

      *(uint4*)(sFH + L * 80 +  0) =
          make_uint4(fw2[rr][0],  fw2[rr][1],  fw2[rr][2],  fw2[rr][3]);
      *(uint4*)(sFH + L * 80 + 16) =
          make_uint4(fw2[rr][4],  fw2[rr][5],  fw2[rr][6],  fw2[rr][7]);
      *(uint4*)(sFH + L * 80 + 32) =
          make_uint4(fw2[rr][8],  fw2[rr][9],  fw2[rr][10], fw2[rr][11]);
      *(uint4*)(sFH + L * 80 + 48) =
          make_uint4(fw2[rr][12], fw2[rr][13], fw2[rr][14], fw2[rr][15]);

      // F tiles into regs; region is then reused for the H-halves
      short8 bfr[4];
      #pragma unroll
      for (int b = 0; b < 4; ++b)
        bfr[b] = *(const short8*)(sFH + (16 * b + r16) * 80 + g * 16);

      f32x4 oacc[4];
      #pragma unroll
      for (int b = 0; b < 4; ++b) oacc[b] = (f32x4){0.f, 0.f, 0.f, 0.f};

      #pragma unroll
      for (int h = 0; h < 2; ++h) {
        // layer 1, half h: a in {2h, 2h+1} -> H cols [32h, 32h+32)
        #pragma unroll
        for (int ai = 0; ai < 2; ++ai) {
          const int a = 2 * h + ai;
          short8 afr = *(const short8*)(smem + (16 * a + r16) * 80 + g * 16);
          f32x4 acc[4];
          #pragma unroll
          for (int b = 0; b < 4; ++b) acc[b] = (f32x4){0.f, 0.f, 0.f, 0.f};
          #pragma unroll
          for (int b = 0; b < 4; ++b)
            acc[b] = __builtin_amdgcn_mfma_f32_16x16x32_bf16(afr, bfr[b],
                                                             acc[b], 0, 0, 0);
          #pragma unroll
          for (int b = 0; b < 4; ++b) {
            f32x4 hh = acc[b];
            float h0 = fmaxf(hh.x, 0.f), h1 = fmaxf(hh.y, 0.f);
            float h2 = fmaxf(hh.z, 0.f), h3 = fmaxf(hh.w, 0.f);
            const int row = 16 * b + r16;
            *(uint2*)(sFH + row * 64 +
                      ((ai * 32 + g * 8) ^ ((row & 3) << 4))) =
                make_uint2(bf2pack(h0, h1), bf2pack(h2, h3));
          }
        }
        // layer 2, k-slice h
        short8 a2 = *(const short8*)(smem + 5120 + r16 * 128 +
                                     ((h * 64 + g * 16) ^ ((r16 & 7) << 4)));
        #pragma unroll
        for (int b = 0; b < 4; ++b) {
          const int row = 16 * b + r16;
          short8 b2 = *(const short8*)(sFH + row * 64 +
                                       ((g * 16) ^ ((row & 3) << 4)));
          oacc[b] = __builtin_amdgcn_mfma_f32_16x16x32_bf16(a2, b2, oacc[b],
                                                            0, 0, 0);
        }
      }

      // corner blend: outacc += wc_r(point m) * O_r
      float wcr = ((r & 1) ? u : 1.0f - u) * ((r & 2) ? v : 1.0f - v);
      #pragma unroll
      for (int b = 0; b < 4; ++b) {
        float wcm = __shfl(wcr, 16 * b + r16, 64);
        outacc[b].x = fmaf(wcm, oacc[b].x, outacc[b].x);
        outacc[b].y = fmaf(wcm, oacc[b].y, outacc[b].y);
        outacc[b].z = fmaf(wcm, oacc[b].z, outacc[b].z);
        outacc[b].w = fmaf(wcm, oacc[b].w, outacc[b].w);
      }
    }
  }

  // ---- store: lane (r16, g<2) holds point 16b+r16, outputs 4g..4g+3 ----
  if (g < 2) {
    #pragma unroll
    for (int b = 0; b < 4; ++b) {
      int pt = blockIdx.x * 256 + w * 64 + 16 * b + r16;
      *(f32x4*)(out + (size_t)pt * 8 + 4 * g) = outacc[b];
    }
  }
}

// ============================================================================
// Fallback kernel (old structure, 4 threads/point): TBF=1 packed / TBF=0 fp32
// ============================================================================
template <int TBF>
__global__ __launch_bounds__(256, 4) void plane_fwd(
    const F2* __restrict__ xy,
    const F2* __restrict__ table,
    const unsigned* __restrict__ tbf16,
    const float* __restrict__ w0g,
    const float* __restrict__ w1g,
    const int* __restrict__ boundp,
    float* __restrict__ out,
    EncParams P)
{
  __shared__ __align__(16) char smem[SMEM_FB];
  const int t = threadIdx.x;
  const int L = t & 63;
  const int w = t >> 6;
  const int r16 = L & 15;
  const int g = L >> 4;

  {
    const float4* s = (const float4*)w0g;
    float4 a = s[t * 2], b = s[t * 2 + 1];
    uint4 pk = make_uint4(bf2pack(a.x, a.y), bf2pack(a.z, a.w),
                          bf2pack(b.x, b.y), bf2pack(b.z, b.w));
    *(uint4*)(smem + (t >> 2) * 80 + (t & 3) * 16) = pk;
  }
  {
    int row = t >> 4;
    int colb = (t & 15) * 8;
    float c0 = 0.f, c1 = 0.f, c2 = 0.f, c3 = 0.f;
    if (row < 8) {
      float4 wv = *(const float4*)(w1g + row * 64 + (t & 15) * 4);
      c0 = wv.x; c1 = wv.y; c2 = wv.z; c3 = wv.w;
    }
    *(uint2*)(smem + 5120 + row * 128 + (colb ^ ((row & 7) << 4))) =
        make_uint2(bf2pack(c0, c1), bf2pack(c2, c3));
  }

  char* sFH = smem + 7168 + w * 8192;

  const int gid = blockIdx.x * 256 + t;
  const int p = gid >> 2;
  const int c = t & 3;
  F2 pxy = xy[p];

  int braw = boundp[0];
  float bf = (braw > 0x00800000) ? __int_as_float(braw) : (float)braw;
  float inv2b = 0.5f / bf;
  float xn = (pxy.x + bf) * inv2b;
  float yn = (pxy.y + bf) * inv2b;

  float cx  = fminf(fmaxf(xn * 2048.0f - 0.5f, 0.0f), 2047.0f);
  float cyv = fminf(fmaxf(yn * 2048.0f - 0.5f, 0.0f), 2047.0f);
  float cx0 = floorf(cx), cy0 = floorf(cyv);
  float u = cx - cx0, v = cyv - cy0;
  float cx1 = fminf(cx0 + 1.0f, 2047.0f);
  float cy1 = fminf(cy0 + 1.0f, 2047.0f);

  const float cxc = (c & 1) ? cx1 : cx0;
  const float cyc = (c & 2) ? cy1 : cy0;
  const float wc = ((c & 1) ? u : 1.0f - u) * ((c & 2) ? v : 1.0f - v);

  const float K = 1.0f / 2048.0f;
  const float gx = (cxc + 0.5f) * K;
  const float gy = (cyc + 0.5f) * K;

  unsigned fw[16];

  #pragma unroll
  for (int lidx = 0; lidx < 16; ++lidx) {
    const int l = (lidx < 4) ? (12 + lidx) : (lidx - 4);
    const float scale   = P.lv[l].scale;
    const unsigned res  = P.lv[l].res;
    const unsigned size = P.lv[l].size;
    const unsigned off  = P.lv[l].offset;
    const bool hashed = (res * res) > size;

    float px = fmaf(gx, scale, 0.5f);
    float pgx = floorf(px);
    float frx = px - pgx;
    unsigned ux = (unsigned)pgx;

    float py = fmaf(gy, scale, 0.5f);
    float pgy = floorf(py);
    float fry = py - pgy;
    unsigned uy = (unsigned)pgy;

    unsigned i00, i01, i10, i11;
    if (hashed) {
      const unsigned m = size - 1u;
      unsigned hy0 = uy * PRIME_Y;
      unsigned hy1 = hy0 + PRIME_Y;
      i00 = (ux ^ hy0) & m;
      i01 = (ux ^ hy1) & m;
      i10 = ((ux + 1u) ^ hy0) & m;
      i11 = ((ux + 1u) ^ hy1) & m;
    } else {
      unsigned b0 = uy * res, b1 = b0 + res;
      unsigned q00 = ux + b0,      q01 = ux + b1;
      unsigned q10 = ux + 1u + b0, q11 = ux + 1u + b1;
      i00 = q00 >= size ? q00 - size : q00;
      i01 = q01 >= size ? q01 - size : q01;
      i10 = q10 >= size ? q10 - size : q10;
      i11 = q11 >= size ? q11 - size : q11;
    }

    F2 t00, t01, t10, t11;
    if (TBF == 1) {
      const unsigned* tb = tbf16 + off;
      t00 = bf2unpack(tb[i00]);
      t01 = bf2unpack(tb[i01]);
      t10 = bf2unpack(tb[i10]);
      t11 = bf2unpack(tb[i11]);
    } else {
      const F2* tabp = table + off;
      t00 = tabp[i00]; t01 = tabp[i01]; t10 = tabp[i10]; t11 = tabp[i11];
    }

    float wx0 = 1.0f - frx, wx1 = frx;
    float wy0 = 1.0f - fry, wy1 = fry;
    float w00 = wx0 * wy0, w01 = wx0 * wy1, w10 = wx1 * wy0, w11 = wx1 * wy1;
    float fx = w00 * t00.x + w01 * t01.x + w10 * t10.x + w11 * t11.x;
    float fy = w00 * t00.y + w01 * t01.y + w10 * t10.y + w11 * t11.y;
    fw[l] = bf2pack(fx, fy);
  }

  *(uint4*)(sFH + L * 80 +  0) = make_uint4(fw[0],  fw[1],  fw[2],  fw[3]);
  *(uint4*)(sFH + L * 80 + 16) = make_uint4(fw[4],  fw[5],  fw[6],  fw[7]);
  *(uint4*)(sFH + L * 80 + 32) = make_uint4(fw[8],  fw[9],  fw[10], fw[11]);
  *(uint4*)(sFH + L * 80 + 48) = make_uint4(fw[12], fw[13], fw[14], fw[15]);

  __syncthreads();

  short8 afr[4], bfr[4];
  #pragma unroll
  for (int b = 0; b < 4; ++b)
    bfr[b] = *(const short8*)(sFH + (16 * b + r16) * 80 + g * 16);
  #pragma unroll
  for (int a = 0; a < 4; ++a)
    afr[a] = *(const short8*)(smem + (16 * a + r16) * 80 + g * 16);

  f32x4 acc[4][4];
  #pragma unroll
  for (int a = 0; a < 4; ++a)
    #pragma unroll
    for (int b = 0; b < 4; ++b)
      acc[a][b] = (f32x4){0.f, 0.f, 0.f, 0.f};

  #pragma unroll
  for (int a = 0; a < 4; ++a)
    #pragma unroll
    for (int b = 0; b < 4; ++b)
      acc[a][b] = __builtin_amdgcn_mfma_f32_16x16x32_bf16(
          afr[a], bfr[b], acc[a][b], 0, 0, 0);

  #pragma unroll
  for (int a = 0; a < 4; ++a)
    #pragma unroll
    for (int b = 0; b < 4; ++b) {
      f32x4 h = acc[a][b];
      float h0 = fmaxf(h.x, 0.f), h1 = fmaxf(h.y, 0.f);
      float h2 = fmaxf(h.z, 0.f), h3 = fmaxf(h.w, 0.f);
      *(uint2*)(sFH + (16 * b + r16) * 128 +
                ((a * 32 + g * 8) ^ ((r16 & 7) << 4))) =
          make_uint2(bf2pack(h0, h1), bf2pack(h2, h3));
    }

  f32x4 oacc[4];
  #pragma unroll
  for (int b = 0; b < 4; ++b) oacc[b] = (f32x4){0.f, 0.f, 0.f, 0.f};

  #pragma unroll
  for (int ks = 0; ks < 2; ++ks) {
    short8 a2 = *(const short8*)(smem + 5120 + r16 * 128 +
                                 ((ks * 64 + g * 16) ^ ((r16 & 7) << 4)));
    #pragma unroll
    for (int b = 0; b < 4; ++b) {
      short8 b2 = *(const short8*)(sFH + (16 * b + r16) * 128 +
                                   ((ks * 64 + g * 16) ^ ((r16 & 7) << 4)));
      oacc[b] = __builtin_amdgcn_mfma_f32_16x16x32_bf16(a2, b2, oacc[b], 0, 0, 0);
    }
  }

  #pragma unroll
  for (int b = 0; b < 4; ++b) {
    float wcm = __shfl(wc, 16 * b + r16, 64);
    float v0 = oacc[b].x * wcm;
    float v1 = oacc[b].y * wcm;
    float v2 = oacc[b].z * wcm;
    float v3 = oacc[b].w * wcm;
    v0 += __shfl_xor(v0, 1, 64); v0 += __shfl_xor(v0, 2, 64);
    v1 += __shfl_xor(v1, 1, 64); v1 += __shfl_xor(v1, 2, 64);
    v2 += __shfl_xor(v2, 1, 64); v2 += __shfl_xor(v2, 2, 64);
    v3 += __shfl_xor(v3, 1, 64); v3 += __shfl_xor(v3, 2, 64);
    if ((L & 3) == 0 && g < 2) {
      int pt = blockIdx.x * 64 + w * 16 + 4 * b + (r16 >> 2);
      *(f32x4*)(out + (size_t)pt * 8 + 4 * g) = (f32x4){v0, v1, v2, v3};
    }
  }
}

extern "C" void kernel_launch(void* const* d_in, const int* in_sizes, int n_in,
                              void* d_out, int out_size, void* d_ws, size_t ws_size,
                              hipStream_t stream) {
  EncParams P;
  double b = exp2(log2(2048.0 / 16.0) / 15.0);
  unsigned off = 0;
  for (int l = 0; l < 16; ++l) {
    double s = 16.0 * pow(b, (double)l) - 1.0;
    int r = (int)ceil(s) + 1;
    unsigned p = (unsigned)(r * r);
    if (p > 524288u) p = 524288u;
    p = (p + 7u) / 8u * 8u;
    P.lv[l].scale = (float)s;
    P.lv[l].res = (unsigned)r;
    P.lv[l].size = p;
    P.lv[l].offset = off;
    off += p;
  }
  const int total_params = (int)off;

  int hstart = 16;
  for (int l = 0; l < 16; ++l) {
    unsigned long long rr = (unsigned long long)P.lv[l].res * P.lv[l].res;
    if (rr > P.lv[l].size) { hstart = l; break; }
  }
  const unsigned denseTotal = (hstart < 16) ? P.lv[hstart].offset
                                            : (unsigned)total_params;
  const size_t quadBytes = (size_t)denseTotal * 16;
  const size_t hashBytes = (size_t)((unsigned)total_params - denseTotal) * 4;
  const size_t packBytes = (size_t)total_params * 4;

  const int N = in_sizes[0] / 2;  // xy is [N,2]
  const F2* xy = (const F2*)d_in[0];
  const F2* table = (const F2*)d_in[1];
  const float* w0g = (const float*)d_in[2];
  const float* w1g = (const float*)d_in[3];
  const int* bp = (const int*)d_in[4];
  float* outp = (float*)d_out;

  if (hstart == 12 && (N & 255) == 0 && ws_size >= quadBytes + hashBytes) {
    uint4* quad = (uint4*)d_ws;
    unsigned* hp = (unsigned*)((char*)d_ws + quadBytes);
    prep3<<<(total_params + 255) / 256, 256, 0, stream>>>(
        table, quad, hp, P, denseTotal, (unsigned)total_params);
    plane_fwd1<<<N / 256, 256, 0, stream>>>(xy, quad, hp, w0g, w1g, bp,
                                            outp, P);
  } else if (ws_size >= packBytes) {
    unsigned* tbf = (unsigned*)d_ws;
    cvt_table<<<(total_params + 255) / 256, 256, 0, stream>>>(table, tbf,
                                                              total_params);
    plane_fwd<1><<<N / 64, 256, 0, stream>>>(xy, table, tbf, w0g, w1g, bp,
                                             outp, P);
  } else {
    plane_fwd<0><<<N / 64, 256, 0, stream>>>(xy, table, nullptr, w0g, w1g, bp,
                                             outp, P);
  }
}

// Round 8
// 279.696 us; speedup vs baseline: 1.2745x; 1.2745x over previous
//
#include <hip/hip_runtime.h>
#include <math.h>

#define PRIME_Y 2654435761u

struct LevelParams { float scale; unsigned res; unsigned size; unsigned offset; };
struct EncParams { LevelParams lv[16]; };

typedef __attribute__((ext_vector_type(8))) short short8;
typedef __attribute__((ext_vector_type(4))) float f32x4;

struct alignas(8) F2 { float x, y; };

// fp32 pair -> packed bf16 (RNE), low = a, high = b.
__device__ inline unsigned bf2pack(float a, float b) {
  unsigned r;
  asm("v_cvt_pk_bf16_f32 %0, %1, %2" : "=v"(r) : "v"(a), "v"(b));
  return r;
}
__device__ inline F2 bf2unpack(unsigned u) {
  F2 r;
  r.x = __uint_as_float(u << 16);
  r.y = __uint_as_float(u & 0xFFFF0000u);
  return r;
}

// Fallback: full table fp32 [n][2] -> packed bf16 [n]
__global__ __launch_bounds__(256) void cvt_table(const F2* __restrict__ in,
                                                 unsigned* __restrict__ outb,
                                                 int n) {
  int i = blockIdx.x * 256 + threadIdx.x;
  if (i < n) {
    F2 v = in[i];
    outb[i] = bf2pack(v.x, v.y);
  }
}

// Prep. Dense [0,denseTotal): quad[v] = packed-bf16
// (T[v], T[(v+1)%sz], T[(v+res)%sz], T[(v+res+1)%sz]) -- one 16B load serves a
// full bilinear cell, wraps folded at build (exact reference semantics).
// Hashed [denseTotal,total): packed bf16 (4B), stored at hp[i-denseTotal].
__global__ __launch_bounds__(256) void prep3(
    const F2* __restrict__ in, uint4* __restrict__ quad,
    unsigned* __restrict__ hp, EncParams P, unsigned denseTotal,
    unsigned total) {
  unsigned i = blockIdx.x * 256 + threadIdx.x;
  if (i >= total) return;
  if (i >= denseTotal) {
    F2 a = in[i];
    hp[i - denseTotal] = bf2pack(a.x, a.y);
    return;
  }
  unsigned off = 0, size = 0, res = 0;
  #pragma unroll
  for (int l = 0; l < 12; ++l)
    if (i >= P.lv[l].offset) {
      off = P.lv[l].offset; size = P.lv[l].size; res = P.lv[l].res;
    }
  unsigned j = i - off;
  unsigned j1 = j + 1u;        if (j1 >= size) j1 -= size;
  unsigned j2 = j + res;       if (j2 >= size) j2 -= size;
  unsigned j3 = j + res + 1u;  if (j3 >= size) j3 -= size;
  F2 a0 = in[off + j],  a1 = in[off + j1];
  F2 a2 = in[off + j2], a3 = in[off + j3];
  quad[i] = make_uint4(bf2pack(a0.x, a0.y), bf2pack(a1.x, a1.y),
                       bf2pack(a2.x, a2.y), bf2pack(a3.x, a3.y));
}

// LDS map (bytes) -- R4 layout (best measured structure, 172us):
//   [0,5120)     sW0  bf16 [64 rows][32] row stride 80
//   [5120,7168)  sW1  bf16 [16 rows][64] stride 128, XOR-swizzled (row&7)<<4
//   [7168,39936) per-wave region, 8192 B each: F bf16 [64][32] stride 80,
//                then overwritten by reluH bf16 [64][64] stride 128 swizzled
// R6/R7 lessons: the 5-blocks/CU path requires <=102 regs -> unreachable
// without spilling the 64-reg fw bridge (R6: +560MB scratch traffic) or
// double-fetching dense quads (R7: FETCH 2x, dur +64%). 4 blocks/CU stands.
#define SMEM_BYTES 39936

// ============================================================================
// Primary kernel: 1 thread = 1 point (R4 structure) + R8 change: branchless
// two-phase hashed gathers. All 36 hashed loads (4 levels x 3x3, no exec-mask
// regions) issue into hv[4][9] BEFORE the dense phase; dense runs fine-first
// (11..6, the other L2-missers) under the hashed flight; hashed consume frees
// 36 regs before dense 5..0 fills the rest of fw. Dense qB is unconditional
// (same 64B line as qA ~75%) with a branchless wrap clamp; qC/qD stay masked.
// ============================================================================
__global__ __launch_bounds__(256, 4) void plane_fwd1(
    const F2* __restrict__ xy,
    const uint4* __restrict__ qtab,     // dense quads, absolute entry index
    const unsigned* __restrict__ hp,    // hashed packed, base = denseTotal
    const float* __restrict__ w0g,
    const float* __restrict__ w1g,
    const int* __restrict__ boundp,
    float* __restrict__ out,
    EncParams P)
{
  __shared__ __align__(16) char smem[SMEM_BYTES];
  const int t = threadIdx.x;
  const int L = t & 63;
  const int w = t >> 6;
  const int r16 = L & 15;
  const int g = L >> 4;

  // ---- stage W0 (bf16, stride 80) ----
  {
    const float4* s = (const float4*)w0g;
    float4 a = s[t * 2], b = s[t * 2 + 1];
    uint4 pk = make_uint4(bf2pack(a.x, a.y), bf2pack(a.z, a.w),
                          bf2pack(b.x, b.y), bf2pack(b.z, b.w));
    *(uint4*)(smem + (t >> 2) * 80 + (t & 3) * 16) = pk;
  }
  // ---- stage W1 (bf16, [16][64] stride 128 swizzled, rows 8..15 = 0) ----
  {
    int row = t >> 4;
    int colb = (t & 15) * 8;
    float c0 = 0.f, c1 = 0.f, c2 = 0.f, c3 = 0.f;
    if (row < 8) {
      float4 wv = *(const float4*)(w1g + row * 64 + (t & 15) * 4);
      c0 = wv.x; c1 = wv.y; c2 = wv.z; c3 = wv.w;
    }
    *(uint2*)(smem + 5120 + row * 128 + (colb ^ ((row & 7) << 4))) =
        make_uint2(bf2pack(c0, c1), bf2pack(c2, c3));
  }

  char* sFH = smem + 7168 + w * 8192;

  // ---- per-point setup ----
  const int pt0 = blockIdx.x * 256 + t;
  F2 pxy = xy[pt0];

  int braw = boundp[0];
  float bf = (braw > 0x00800000) ? __int_as_float(braw) : (float)braw;
  float inv2b = 0.5f / bf;
  float xn = (pxy.x + bf) * inv2b;
  float yn = (pxy.y + bf) * inv2b;

  float cx  = fminf(fmaxf(xn * 2048.0f - 0.5f, 0.0f), 2047.0f);
  float cyv = fminf(fmaxf(yn * 2048.0f - 0.5f, 0.0f), 2047.0f);
  float cx0 = floorf(cx), cy0 = floorf(cyv);
  float u = cx - cx0, v = cyv - cy0;
  float cx1 = fminf(cx0 + 1.0f, 2047.0f);
  float cy1 = fminf(cy0 + 1.0f, 2047.0f);

  const float K = 1.0f / 2048.0f;
  const float gxc0 = (cx0 + 0.5f) * K, gxc1 = (cx1 + 0.5f) * K;
  const float gyc0 = (cy0 + 0.5f) * K, gyc1 = (cy1 + 0.5f) * K;

  unsigned fw[4][16];           // [corner][level], all indices static
  const unsigned denseOff = P.lv[12].offset;

  // ==== phase 1: issue all 36 hashed gathers (branchless, no exec masks) ====
  unsigned hv[4][9];   // hv[li][j*3+i] = entry at (x0+i, y0+j)
  #pragma unroll
  for (int li = 0; li < 4; ++li) {
    const int l = 12 + li;
    const float scale   = P.lv[l].scale;
    const unsigned size = P.lv[l].size;
    const unsigned off  = P.lv[l].offset;
    const unsigned m = size - 1u;          // size == 2^19
    const unsigned* tb = hp + (off - denseOff);

    float px0 = fmaf(gxc0, scale, 0.5f);
    float py0 = fmaf(gyc0, scale, 0.5f);
    unsigned ux0 = (unsigned)floorf(px0);
    unsigned uy0 = (unsigned)floorf(py0);
    unsigned hy0 = uy0 * PRIME_Y;
    unsigned hy1 = hy0 + PRIME_Y;
    unsigned hy2 = hy1 + PRIME_Y;
    hv[li][0] = tb[(ux0      ^ hy0) & m];
    hv[li][1] = tb[((ux0+1u) ^ hy0) & m];
    hv[li][2] = tb[((ux0+2u) ^ hy0) & m];
    hv[li][3] = tb[(ux0      ^ hy1) & m];
    hv[li][4] = tb[((ux0+1u) ^ hy1) & m];
    hv[li][5] = tb[((ux0+2u) ^ hy1) & m];
    hv[li][6] = tb[(ux0      ^ hy2) & m];
    hv[li][7] = tb[((ux0+1u) ^ hy2) & m];
    hv[li][8] = tb[((ux0+2u) ^ hy2) & m];
  }

  // ==== phase 2a: dense levels 11..6 (fine, L2-miss-prone) under the
  //      hashed flight ====
  #pragma unroll
  for (int li = 0; li < 6; ++li) {
    const int l = 11 - li;
    const float scale   = P.lv[l].scale;
    const unsigned res  = P.lv[l].res;
    const unsigned size = P.lv[l].size;
    const unsigned off  = P.lv[l].offset;
    const uint4* qt = qtab + off;

    float px0 = fmaf(gxc0, scale, 0.5f), px1 = fmaf(gxc1, scale, 0.5f);
    float py0 = fmaf(gyc0, scale, 0.5f), py1 = fmaf(gyc1, scale, 0.5f);
    float fx0 = floorf(px0), fx1 = floorf(px1);
    float fy0 = floorf(py0), fy1 = floorf(py1);
    unsigned ux0 = (unsigned)fx0, ux1 = (unsigned)fx1;
    unsigned uy0 = (unsigned)fy0, uy1 = (unsigned)fy1;
    bool xs = (ux1 != ux0), ys = (uy1 != uy0);

    unsigned vA = ux0 + uy0 * res;       // < size always
    unsigned vB = vA + 1u;               // <= size; == size only when !xs
    if (vB >= size) vB = 0u;             // branchless clamp (value unused then)
    uint4 qA = qt[vA];
    uint4 qB = qt[vB];                   // same 64B line as qA ~75% of cases
    uint4 qC = make_uint4(0u, 0u, 0u, 0u);
    uint4 qD = make_uint4(0u, 0u, 0u, 0u);
    if (ys) {
      unsigned vC = vA + res;            // valid: ys -> uy0 <= res-2
      unsigned vD = vC + 1u;             // == size only when !xs (unused)
      if (vD >= size) vD = 0u;
      qC = qt[vC];
      qD = qt[vD];
    }

    float frx0 = px0 - fx0, frx1 = px1 - fx1;
    float fry0 = py0 - fy0, fry1 = py1 - fy1;

    #pragma unroll
    for (int c = 0; c < 4; ++c) {
      const bool cH = (c & 1) != 0, cV = (c & 2) != 0;
      bool sx = cH && xs, sy = cV && ys;
      unsigned qx = sy ? (sx ? qD.x : qC.x) : (sx ? qB.x : qA.x);
      unsigned qy = sy ? (sx ? qD.y : qC.y) : (sx ? qB.y : qA.y);
      unsigned qz = sy ? (sx ? qD.z : qC.z) : (sx ? qB.z : qA.z);
      unsigned qw = sy ? (sx ? qD.w : qC.w) : (sx ? qB.w : qA.w);
      float frx = cH ? frx1 : frx0;
      float fry = cV ? fry1 : fry0;
      F2 t00 = bf2unpack(qx), t10 = bf2unpack(qy);
      F2 t01 = bf2unpack(qz), t11 = bf2unpack(qw);
      float wx0 = 1.0f - frx, wx1 = frx;
      float wy0 = 1.0f - fry, wy1 = fry;
      float w00 = wx0 * wy0, w01 = wx0 * wy1, w10 = wx1 * wy0, w11 = wx1 * wy1;
      float fx = w00 * t00.x + w01 * t01.x + w10 * t10.x + w11 * t11.x;
      float fy = w00 * t00.y + w01 * t01.y + w10 * t10.y + w11 * t11.y;
      fw[c][l] = bf2pack(fx, fy);
    }
  }

  // ==== phase 2b: consume hashed (frees hv's 36 regs before fw fills) ====
  #pragma unroll
  for (int li = 0; li < 4; ++li) {
    const int l = 12 + li;
    const float scale = P.lv[l].scale;
    float px0 = fmaf(gxc0, scale, 0.5f), px1 = fmaf(gxc1, scale, 0.5f);
    float py0 = fmaf(gyc0, scale, 0.5f), py1 = fmaf(gyc1, scale, 0.5f);
    float fx0 = floorf(px0), fx1 = floorf(px1);
    float fy0 = floorf(py0), fy1 = floorf(py1);
    bool xs = ((unsigned)fx1 != (unsigned)fx0);
    bool ys = ((unsigned)fy1 != (unsigned)fy0);
    float frx0 = px0 - fx0, frx1 = px1 - fx1;
    float fry0 = py0 - fy0, fry1 = py1 - fy1;

    #pragma unroll
    for (int c = 0; c < 4; ++c) {
      const bool cH = (c & 1) != 0, cV = (c & 2) != 0;
      bool sx = cH && xs, sy = cV && ys;
      // entry(dx,dy) = hv[li][(dy+sy)*3 + (dx+sx)]
      unsigned e00 = sy ? (sx ? hv[li][4] : hv[li][3])
                        : (sx ? hv[li][1] : hv[li][0]);
      unsigned e10 = sy ? (sx ? hv[li][5] : hv[li][4])
                        : (sx ? hv[li][2] : hv[li][1]);
      unsigned e01 = sy ? (sx ? hv[li][7] : hv[li][6])
                        : (sx ? hv[li][4] : hv[li][3]);
      unsigned e11 = sy ? (sx ? hv[li][8] : hv[li][7])
                        : (sx ? hv[li][5] : hv[li][4]);
      float frx = cH ? frx1 : frx0;
      float fry = cV ? fry1 : fry0;
      F2 t00 = bf2unpack(e00), t10 = bf2unpack(e10);
      F2 t01 = bf2unpack(e01), t11 = bf2unpack(e11);
      float wx0 = 1.0f - frx, wx1 = frx;
      float wy0 = 1.0f - fry, wy1 = fry;
      float w00 = wx0 * wy0, w01 = wx0 * wy1, w10 = wx1 * wy0, w11 = wx1 * wy1;
      float fx = w00 * t00.x + w01 * t01.x + w10 * t10.x + w11 * t11.x;
      float fy = w00 * t00.y + w01 * t01.y + w10 * t10.y + w11 * t11.y;
      fw[c][l] = bf2pack(fx, fy);
    }
  }

  // ==== phase 2c: dense levels 5..0 (small tables, L2-resident) ====
  #pragma unroll
  for (int li = 0; li < 6; ++li) {
    const int l = 5 - li;
    const float scale   = P.lv[l].scale;
    const unsigned res  = P.lv[l].res;
    const unsigned size = P.lv[l].size;
    const unsigned off  = P.lv[l].offset;
    const uint4* qt = qtab + off;

    float px0 = fmaf(gxc0, scale, 0.5f), px1 = fmaf(gxc1, scale, 0.5f);
    float py0 = fmaf(gyc0, scale, 0.5f), py1 = fmaf(gyc1, scale, 0.5f);
    float fx0 = floorf(px0), fx1 = floorf(px1);
    float fy0 = floorf(py0), fy1 = floorf(py1);
    unsigned ux0 = (unsigned)fx0, ux1 = (unsigned)fx1;
    unsigned uy0 = (unsigned)fy0, uy1 = (unsigned)fy1;
    bool xs = (ux1 != ux0), ys = (uy1 != uy0);

    unsigned vA = ux0 + uy0 * res;
    unsigned vB = vA + 1u;
    if (vB >= size) vB = 0u;
    uint4 qA = qt[vA];
    uint4 qB = qt[vB];
    uint4 qC = make_uint4(0u, 0u, 0u, 0u);
    uint4 qD = make_uint4(0u, 0u, 0u, 0u);
    if (ys) {
      unsigned vC = vA + res;
      unsigned vD = vC + 1u;
      if (vD >= size) vD = 0u;
      qC = qt[vC];
      qD = qt[vD];
    }

    float frx0 = px0 - fx0, frx1 = px1 - fx1;
    float fry0 = py0 - fy0, fry1 = py1 - fy1;

    #pragma unroll
    for (int c = 0; c < 4; ++c) {
      const bool cH = (c & 1) != 0, cV = (c & 2) != 0;
      bool sx = cH && xs, sy = cV && ys;
      unsigned qx = sy ? (sx ? qD.x : qC.x) : (sx ? qB.x : qA.x);
      unsigned qy = sy ? (sx ? qD.y : qC.y) : (sx ? qB.y : qA.y);
      unsigned qz = sy ? (sx ? qD.z : qC.z) : (sx ? qB.z : qA.z);
      unsigned qw = sy ? (sx ? qD.w : qC.w) : (sx ? qB.w : qA.w);
      float frx = cH ? frx1 : frx0;
      float fry = cV ? fry1 : fry0;
      F2 t00 = bf2unpack(qx), t10 = bf2unpack(qy);
      F2 t01 = bf2unpack(qz), t11 = bf2unpack(qw);
      float wx0 = 1.0f - frx, wx1 = frx;
      float wy0 = 1.0f - fry, wy1 = fry;
      float w00 = wx0 * wy0, w01 = wx0 * wy1, w10 = wx1 * wy0, w11 = wx1 * wy1;
      float fx = w00 * t00.x + w01 * t01.x + w10 * t10.x + w11 * t11.x;
      float fy = w00 * t00.y + w01 * t01.y + w10 * t10.y + w11 * t11.y;
      fw[c][l] = bf2pack(fx, fy);
    }
  }

  __syncthreads();   // W0/W1 staging visible to all waves

  f32x4 outacc[4];
  #pragma unroll
  for (int b = 0; b < 4; ++b) outacc[b] = (f32x4){0.f, 0.f, 0.f, 0.f};

  // ---- 4 MFMA rounds: round r = corner r of the wave's 64 points ----
  // All F/H traffic is wave-private; in-wave DS ordering (lgkmcnt) provides
  // write->read ordering without barriers.
  #pragma unroll
  for (int r = 0; r < 4; ++r) {
    *(uint4*)(sFH + L * 80 +  0) =
        make_uint4(fw[r][0],  fw[r][1],  fw[r][2],  fw[r][3]);
    *(uint4*)(sFH + L * 80 + 16) =
        make_uint4(fw[r][4],  fw[r][5],  fw[r][6],  fw[r][7]);
    *(uint4*)(sFH + L * 80 + 32) =
        make_uint4(fw[r][8],  fw[r][9],  fw[r][10], fw[r][11]);
    *(uint4*)(sFH + L * 80 + 48) =
        make_uint4(fw[r][12], fw[r][13], fw[r][14], fw[r][15]);

    // F tiles into regs before H writes clobber the region
    short8 bfr[4];
    #pragma unroll
    for (int b = 0; b < 4; ++b)
      bfr[b] = *(const short8*)(sFH + (16 * b + r16) * 80 + g * 16);

    // layer 1, a-sliced (acc = 16 VGPRs instead of 64)
    #pragma unroll
    for (int a = 0; a < 4; ++a) {
      short8 afr = *(const short8*)(smem + (16 * a + r16) * 80 + g * 16);
      f32x4 acc[4];
      #pragma unroll
      for (int b = 0; b < 4; ++b) acc[b] = (f32x4){0.f, 0.f, 0.f, 0.f};
      #pragma unroll
      for (int b = 0; b < 4; ++b)
        acc[b] = __builtin_amdgcn_mfma_f32_16x16x32_bf16(afr, bfr[b], acc[b],
                                                         0, 0, 0);
      #pragma unroll
      for (int b = 0; b < 4; ++b) {
        f32x4 h = acc[b];
        float h0 = fmaxf(h.x, 0.f), h1 = fmaxf(h.y, 0.f);
        float h2 = fmaxf(h.z, 0.f), h3 = fmaxf(h.w, 0.f);
        *(uint2*)(sFH + (16 * b + r16) * 128 +
                  ((a * 32 + g * 8) ^ ((r16 & 7) << 4))) =
            make_uint2(bf2pack(h0, h1), bf2pack(h2, h3));
      }
    }

    // layer 2
    f32x4 oacc[4];
    #pragma unroll
    for (int b = 0; b < 4; ++b) oacc[b] = (f32x4){0.f, 0.f, 0.f, 0.f};
    #pragma unroll
    for (int ks = 0; ks < 2; ++ks) {
      short8 a2 = *(const short8*)(smem + 5120 + r16 * 128 +
                                   ((ks * 64 + g * 16) ^ ((r16 & 7) << 4)));
      #pragma unroll
      for (int b = 0; b < 4; ++b) {
        short8 b2 = *(const short8*)(sFH + (16 * b + r16) * 128 +
                                     ((ks * 64 + g * 16) ^ ((r16 & 7) << 4)));
        oacc[b] = __builtin_amdgcn_mfma_f32_16x16x32_bf16(a2, b2, oacc[b],
                                                          0, 0, 0);
      }
    }

    // corner blend: outacc += wc_r(point m) * O_r
    float wcr = ((r & 1) ? u : 1.0f - u) * ((r & 2) ? v : 1.0f - v);
    #pragma unroll
    for (int b = 0; b < 4; ++b) {
      float wcm = __shfl(wcr, 16 * b + r16, 64);
      outacc[b].x = fmaf(wcm, oacc[b].x, outacc[b].x);
      outacc[b].y = fmaf(wcm, oacc[b].y, outacc[b].y);
      outacc[b].z = fmaf(wcm, oacc[b].z, outacc[b].z);
      outacc[b].w = fmaf(wcm, oacc[b].w, outacc[b].w);
    }
  }

  // ---- store: lane (r16, g<2) holds point 16b+r16, outputs 4g..4g+3 ----
  if (g < 2) {
    #pragma unroll
    for (int b = 0; b < 4; ++b) {
      int pt = blockIdx.x * 256 + w * 64 + 16 * b + r16;
      *(f32x4*)(out + (size_t)pt * 8 + 4 * g) = outacc[b];
    }
  }
}

// ============================================================================
// Fallback kernel (old structure, 4 threads/point): TBF=1 packed / TBF=0 fp32
// ============================================================================
template <int TBF>
__global__ __launch_bounds__(256, 4) void plane_fwd(
    const F2* __restrict__ xy,
    const F2* __restrict__ table,
    const unsigned* __restrict__ tbf16,
    const float* __restrict__ w0g,
    const float* __restrict__ w1g,
    const int* __restrict__ boundp,
    float* __restrict__ out,
    EncParams P)
{
  __shared__ __align__(16) char smem[SMEM_BYTES];
  const int t = threadIdx.x;
  const int L = t & 63;
  const int w = t >> 6;
  const int r16 = L & 15;
  const int g = L >> 4;

  {
    const float4* s = (const float4*)w0g;
    float4 a = s[t * 2], b = s[t * 2 + 1];
    uint4 pk = make_uint4(bf2pack(a.x, a.y), bf2pack(a.z, a.w),
                          bf2pack(b.x, b.y), bf2pack(b.z, b.w));
    *(uint4*)(smem + (t >> 2) * 80 + (t & 3) * 16) = pk;
  }
  {
    int row = t >> 4;
    int colb = (t & 15) * 8;
    float c0 = 0.f, c1 = 0.f, c2 = 0.f, c3 = 0.f;
    if (row < 8) {
      float4 wv = *(const float4*)(w1g + row * 64 + (t & 15) * 4);
      c0 = wv.x; c1 = wv.y; c2 = wv.z; c3 = wv.w;
    }
    *(uint2*)(smem + 5120 + row * 128 + (colb ^ ((row & 7) << 4))) =
        make_uint2(bf2pack(c0, c1), bf2pack(c2, c3));
  }

  char* sFH = smem + 7168 + w * 8192;

  const int gid = blockIdx.x * 256 + t;
  const int p = gid >> 2;
  const int c = t & 3;
  F2 pxy = xy[p];

  int braw = boundp[0];
  float bf = (braw > 0x00800000) ? __int_as_float(braw) : (float)braw;
  float inv2b = 0.5f / bf;
  float xn = (pxy.x + bf) * inv2b;
  float yn = (pxy.y + bf) * inv2b;

  float cx  = fminf(fmaxf(xn * 2048.0f - 0.5f, 0.0f), 2047.0f);
  float cyv = fminf(fmaxf(yn * 2048.0f - 0.5f, 0.0f), 2047.0f);
  float cx0 = floorf(cx), cy0 = floorf(cyv);
  float u = cx - cx0, v = cyv - cy0;
  float cx1 = fminf(cx0 + 1.0f, 2047.0f);
  float cy1 = fminf(cy0 + 1.0f, 2047.0f);

  const float cxc = (c & 1) ? cx1 : cx0;
  const float cyc = (c & 2) ? cy1 : cy0;
  const float wc = ((c & 1) ? u : 1.0f - u) * ((c & 2) ? v : 1.0f - v);

  const float K = 1.0f / 2048.0f;
  const float gx = (cxc + 0.5f) * K;
  const float gy = (cyc + 0.5f) * K;

  unsigned fw[16];

  #pragma unroll
  for (int lidx = 0; lidx < 16; ++lidx) {
    const int l = (lidx < 4) ? (12 + lidx) : (lidx - 4);
    const float scale   = P.lv[l].scale;
    const unsigned res  = P.lv[l].res;
    const unsigned size = P.lv[l].size;
    const unsigned off  = P.lv[l].offset;
    const bool hashed = (res * res) > size;

    float px = fmaf(gx, scale, 0.5f);
    float pgx = floorf(px);
    float frx = px - pgx;
    unsigned ux = (unsigned)pgx;

    float py = fmaf(gy, scale, 0.5f);
    float pgy = floorf(py);
    float fry = py - pgy;
    unsigned uy = (unsigned)pgy;

    unsigned i00, i01, i10, i11;
    if (hashed) {
      const unsigned m = size - 1u;
      unsigned hy0 = uy * PRIME_Y;
      unsigned hy1 = hy0 + PRIME_Y;
      i00 = (ux ^ hy0) & m;
      i01 = (ux ^ hy1) & m;
      i10 = ((ux + 1u) ^ hy0) & m;
      i11 = ((ux + 1u) ^ hy1) & m;
    } else {
      unsigned b0 = uy * res, b1 = b0 + res;
      unsigned q00 = ux + b0,      q01 = ux + b1;
      unsigned q10 = ux + 1u + b0, q11 = ux + 1u + b1;
      i00 = q00 >= size ? q00 - size : q00;
      i01 = q01 >= size ? q01 - size : q01;
      i10 = q10 >= size ? q10 - size : q10;
      i11 = q11 >= size ? q11 - size : q11;
    }

    F2 t00, t01, t10, t11;
    if (TBF == 1) {
      const unsigned* tb = tbf16 + off;
      t00 = bf2unpack(tb[i00]);
      t01 = bf2unpack(tb[i01]);
      t10 = bf2unpack(tb[i10]);
      t11 = bf2unpack(tb[i11]);
    } else {
      const F2* tabp = table + off;
      t00 = tabp[i00]; t01 = tabp[i01]; t10 = tabp[i10]; t11 = tabp[i11];
    }

    float wx0 = 1.0f - frx, wx1 = frx;
    float wy0 = 1.0f - fry, wy1 = fry;
    float w00 = wx0 * wy0, w01 = wx0 * wy1, w10 = wx1 * wy0, w11 = wx1 * wy1;
    float fx = w00 * t00.x + w01 * t01.x + w10 * t10.x + w11 * t11.x;
    float fy = w00 * t00.y + w01 * t01.y + w10 * t10.y + w11 * t11.y;
    fw[l] = bf2pack(fx, fy);
  }

  *(uint4*)(sFH + L * 80 +  0) = make_uint4(fw[0],  fw[1],  fw[2],  fw[3]);
  *(uint4*)(sFH + L * 80 + 16) = make_uint4(fw[4],  fw[5],  fw[6],  fw[7]);
  *(uint4*)(sFH + L * 80 + 32) = make_uint4(fw[8],  fw[9],  fw[10], fw[11]);
  *(uint4*)(sFH + L * 80 + 48) = make_uint4(fw[12], fw[13], fw[14], fw[15]);

  __syncthreads();

  short8 afr[4], bfr[4];
  #pragma unroll
  for (int b = 0; b < 4; ++b)
    bfr[b] = *(const short8*)(sFH + (16 * b + r16) * 80 + g * 16);
  #pragma unroll
  for (int a = 0; a < 4; ++a)
    afr[a] = *(const short8*)(smem + (16 * a + r16) * 80 + g * 16);

  f32x4 acc[4][4];
  #pragma unroll
  for (int a = 0; a < 4; ++a)
    #pragma unroll
    for (int b = 0; b < 4; ++b)
      acc[a][b] = (f32x4){0.f, 0.f, 0.f, 0.f};

  #pragma unroll
  for (int a = 0; a < 4; ++a)
    #pragma unroll
    for (int b = 0; b < 4; ++b)
      acc[a][b] = __builtin_amdgcn_mfma_f32_16x16x32_bf16(
          afr[a], bfr[b], acc[a][b], 0, 0, 0);

  #pragma unroll
  for (int a = 0; a < 4; ++a)
    #pragma unroll
    for (int b = 0; b < 4; ++b) {
      f32x4 h = acc[a][b];
      float h0 = fmaxf(h.x, 0.f), h1 = fmaxf(h.y, 0.f);
      float h2 = fmaxf(h.z, 0.f), h3 = fmaxf(h.w, 0.f);
      *(uint2*)(sFH + (16 * b + r16) * 128 +
                ((a * 32 + g * 8) ^ ((r16 & 7) << 4))) =
          make_uint2(bf2pack(h0, h1), bf2pack(h2, h3));
    }

  f32x4 oacc[4];
  #pragma unroll
  for (int b = 0; b < 4; ++b) oacc[b] = (f32x4){0.f, 0.f, 0.f, 0.f};

  #pragma unroll
  for (int ks = 0; ks < 2; ++ks) {
    short8 a2 = *(const short8*)(smem + 5120 + r16 * 128 +
                                 ((ks * 64 + g * 16) ^ ((r16 & 7) << 4)));
    #pragma unroll
    for (int b = 0; b < 4; ++b) {
      short8 b2 = *(const short8*)(sFH + (16 * b + r16) * 128 +
                                   ((ks * 64 + g * 16) ^ ((r16 & 7) << 4)));
      oacc[b] = __builtin_amdgcn_mfma_f32_16x16x32_bf16(a2, b2, oacc[b], 0, 0, 0);
    }
  }

  #pragma unroll
  for (int b = 0; b < 4; ++b) {
    float wcm = __shfl(wc, 16 * b + r16, 64);
    float v0 = oacc[b].x * wcm;
    float v1 = oacc[b].y * wcm;
    float v2 = oacc[b].z * wcm;
    float v3 = oacc[b].w * wcm;
    v0 += __shfl_xor(v0, 1, 64); v0 += __shfl_xor(v0, 2, 64);
    v1 += __shfl_xor(v1, 1, 64); v1 += __shfl_xor(v1, 2, 64);
    v2 += __shfl_xor(v2, 1, 64); v2 += __shfl_xor(v2, 2, 64);
    v3 += __shfl_xor(v3, 1, 64); v3 += __shfl_xor(v3, 2, 64);
    if ((L & 3) == 0 && g < 2) {
      int pt = blockIdx.x * 64 + w * 16 + 4 * b + (r16 >> 2);
      *(f32x4*)(out + (size_t)pt * 8 + 4 * g) = (f32x4){v0, v1, v2, v3};
    }
  }
}

extern "C" void kernel_launch(void* const* d_in, const int* in_sizes, int n_in,
                              void* d_out, int out_size, void* d_ws, size_t ws_size,
                              hipStream_t stream) {
  EncParams P;
  double b = exp2(log2(2048.0 / 16.0) / 15.0);
  unsigned off = 0;
  for (int l = 0; l < 16; ++l) {
    double s = 16.0 * pow(b, (double)l) - 1.0;
    int r = (int)ceil(s) + 1;
    unsigned p = (unsigned)(r * r);
    if (p > 524288u) p = 524288u;
    p = (p + 7u) / 8u * 8u;
    P.lv[l].scale = (float)s;
    P.lv[l].res = (unsigned)r;
    P.lv[l].size = p;
    P.lv[l].offset = off;
    off += p;
  }
  const int total_params = (int)off;

  int hstart = 16;
  for (int l = 0; l < 16; ++l) {
    unsigned long long rr = (unsigned long long)P.lv[l].res * P.lv[l].res;
    if (rr > P.lv[l].size) { hstart = l; break; }
  }
  const unsigned denseTotal = (hstart < 16) ? P.lv[hstart].offset
                                            : (unsigned)total_params;
  const size_t quadBytes = (size_t)denseTotal * 16;
  const size_t hashBytes = (size_t)((unsigned)total_params - denseTotal) * 4;
  const size_t packBytes = (size_t)total_params * 4;

  const int N = in_sizes[0] / 2;  // xy is [N,2]
  const F2* xy = (const F2*)d_in[0];
  const F2* table = (const F2*)d_in[1];
  const float* w0g = (const float*)d_in[2];
  const float* w1g = (const float*)d_in[3];
  const int* bp = (const int*)d_in[4];
  float* outp = (float*)d_out;

  if (hstart == 12 && (N & 255) == 0 && ws_size >= quadBytes + hashBytes) {
    uint4* quad = (uint4*)d_ws;
    unsigned* hp = (unsigned*)((char*)d_ws + quadBytes);
    prep3<<<(total_params + 255) / 256, 256, 0, stream>>>(
        table, quad, hp, P, denseTotal, (unsigned)total_params);
    plane_fwd1<<<N / 256, 256, 0, stream>>>(xy, quad, hp, w0g, w1g, bp,
                                            outp, P);
  } else if (ws_size >= packBytes) {
    unsigned* tbf = (unsigned*)d_ws;
    cvt_table<<<(total_params + 255) / 256, 256, 0, stream>>>(table, tbf,
                                                              total_params);
    plane_fwd<1><<<N / 64, 256, 0, stream>>>(xy, table, tbf, w0g, w1g, bp,
                                             outp, P);
  } else {
    plane_fwd<0><<<N / 64, 256, 0, stream>>>(xy, table, nullptr, w0g, w1g, bp,
                                             outp, P);
  }
}

// Round 9
// 268.146 us; speedup vs baseline: 1.3294x; 1.0431x over previous
//
#include <hip/hip_runtime.h>
#include <math.h>

#define PRIME_Y 2654435761u

struct LevelParams { float scale; unsigned res; unsigned size; unsigned offset; };
struct EncParams { LevelParams lv[16]; };

typedef __attribute__((ext_vector_type(8))) short short8;
typedef __attribute__((ext_vector_type(4))) float f32x4;

struct alignas(8) F2 { float x, y; };

// fp32 pair -> packed bf16 (RNE), low = a, high = b.
__device__ inline unsigned bf2pack(float a, float b) {
  unsigned r;
  asm("v_cvt_pk_bf16_f32 %0, %1, %2" : "=v"(r) : "v"(a), "v"(b));
  return r;
}
__device__ inline F2 bf2unpack(unsigned u) {
  F2 r;
  r.x = __uint_as_float(u << 16);
  r.y = __uint_as_float(u & 0xFFFF0000u);
  return r;
}

// Fallback: full table fp32 [n][2] -> packed bf16 [n]
__global__ __launch_bounds__(256) void cvt_table(const F2* __restrict__ in,
                                                 unsigned* __restrict__ outb,
                                                 int n) {
  int i = blockIdx.x * 256 + threadIdx.x;
  if (i < n) {
    F2 v = in[i];
    outb[i] = bf2pack(v.x, v.y);
  }
}

// Prep. Dense [0,denseTotal): quad[v] = packed-bf16
// (T[v], T[(v+1)%sz], T[(v+res)%sz], T[(v+res+1)%sz]) -- one 16B load serves a
// full bilinear cell, wraps folded at build (exact reference semantics).
// Hashed [denseTotal,total): packed bf16 (4B), stored at hp[i-denseTotal].
__global__ __launch_bounds__(256) void prep3(
    const F2* __restrict__ in, uint4* __restrict__ quad,
    unsigned* __restrict__ hp, EncParams P, unsigned denseTotal,
    unsigned total) {
  unsigned i = blockIdx.x * 256 + threadIdx.x;
  if (i >= total) return;
  if (i >= denseTotal) {
    F2 a = in[i];
    hp[i - denseTotal] = bf2pack(a.x, a.y);
    return;
  }
  unsigned off = 0, size = 0, res = 0;
  #pragma unroll
  for (int l = 0; l < 12; ++l)
    if (i >= P.lv[l].offset) {
      off = P.lv[l].offset; size = P.lv[l].size; res = P.lv[l].res;
    }
  unsigned j = i - off;
  unsigned j1 = j + 1u;        if (j1 >= size) j1 -= size;
  unsigned j2 = j + res;       if (j2 >= size) j2 -= size;
  unsigned j3 = j + res + 1u;  if (j3 >= size) j3 -= size;
  F2 a0 = in[off + j],  a1 = in[off + j1];
  F2 a2 = in[off + j2], a3 = in[off + j3];
  quad[i] = make_uint4(bf2pack(a0.x, a0.y), bf2pack(a1.x, a1.y),
                       bf2pack(a2.x, a2.y), bf2pack(a3.x, a3.y));
}

// Primary-kernel LDS map (bytes) -- R6's proven MLP layout:
//   [0,5120)     sW0  bf16 [64 rows][32] row stride 80
//   [5120,7168)  sW1  bf16 [16 rows][64] stride 128, XOR-swizzled (row&7)<<4
//   [7168,27648) per-wave region, 5120 B each:
//                  F bf16 [64][32] stride 80 (consumed into regs), then
//                  reluH HALF [64 m][32 j] stride 64, swz ^((m&3)<<4)
// 27648 -> LDS cap 5 blocks/CU.
// R8 lesson: branchless hoisting = +57% FETCH, compiler sinks anyway (3rd
// confirmation). R9 attacks occupancy instead: pair-split halves the unified
// reg demand (~120 -> ~90: fw bridge 64 -> 32) so 5 blocks/CU is reachable
// WITHOUT forcing launch bounds (R6's spill) and WITHOUT within-thread
// corner serialization (R7's double-fetch -- the two halves now run in
// adjacent lanes concurrently, shared dense lines coalesce in-wave).
#define SMEM_BYTES 27648
#define SMEM_FB 39936   // fallback kernel keeps the old map

// ============================================================================
// Primary kernel: 2 threads per point. Lane L: point L>>1, role = L&1
// (role 0 -> outer-bilinear corner row y0, role 1 -> y1). Each thread
// encodes its 2 x-corners (R7's proven per-thread encode), then 2 MFMA
// rounds (round rr = x-corner rr; F row = lane). Corner blend via
// shfl(wcr, row); final cross-pair reduce via shfl_xor(...,1).
// ============================================================================
__global__ __launch_bounds__(256, 4) void plane_fwd1(
    const F2* __restrict__ xy,
    const uint4* __restrict__ qtab,     // dense quads, absolute entry index
    const unsigned* __restrict__ hp,    // hashed packed, base = denseTotal
    const float* __restrict__ w0g,
    const float* __restrict__ w1g,
    const int* __restrict__ boundp,
    float* __restrict__ out,
    EncParams P)
{
  __shared__ __align__(16) char smem[SMEM_BYTES];
  const int t = threadIdx.x;
  const int L = t & 63;
  const int w = t >> 6;
  const int r16 = L & 15;
  const int g = L >> 4;
  const int role = L & 1;

  // ---- stage W0 (bf16, stride 80) ----
  {
    const float4* s = (const float4*)w0g;
    float4 a = s[t * 2], b = s[t * 2 + 1];
    uint4 pk = make_uint4(bf2pack(a.x, a.y), bf2pack(a.z, a.w),
                          bf2pack(b.x, b.y), bf2pack(b.z, b.w));
    *(uint4*)(smem + (t >> 2) * 80 + (t & 3) * 16) = pk;
  }
  // ---- stage W1 (bf16, [16][64] stride 128 swizzled, rows 8..15 = 0) ----
  {
    int row = t >> 4;
    int colb = (t & 15) * 8;
    float c0 = 0.f, c1 = 0.f, c2 = 0.f, c3 = 0.f;
    if (row < 8) {
      float4 wv = *(const float4*)(w1g + row * 64 + (t & 15) * 4);
      c0 = wv.x; c1 = wv.y; c2 = wv.z; c3 = wv.w;
    }
    *(uint2*)(smem + 5120 + row * 128 + (colb ^ ((row & 7) << 4))) =
        make_uint2(bf2pack(c0, c1), bf2pack(c2, c3));
  }

  char* sFH = smem + 7168 + w * 5120;

  // ---- per-point setup (both threads of a pair compute identically) ----
  const int pt = blockIdx.x * 128 + w * 32 + (L >> 1);
  F2 pxy = xy[pt];

  int braw = boundp[0];
  float bf = (braw > 0x00800000) ? __int_as_float(braw) : (float)braw;
  float inv2b = 0.5f / bf;
  float xn = (pxy.x + bf) * inv2b;
  float yn = (pxy.y + bf) * inv2b;

  float cx  = fminf(fmaxf(xn * 2048.0f - 0.5f, 0.0f), 2047.0f);
  float cyv = fminf(fmaxf(yn * 2048.0f - 0.5f, 0.0f), 2047.0f);
  float cx0 = floorf(cx), cy0 = floorf(cyv);
  float u = cx - cx0, v = cyv - cy0;
  float cx1 = fminf(cx0 + 1.0f, 2047.0f);
  float cy1 = fminf(cy0 + 1.0f, 2047.0f);

  const float K = 1.0f / 2048.0f;
  const float gxc0 = (cx0 + 0.5f) * K, gxc1 = (cx1 + 0.5f) * K;
  const float gyc0 = (cy0 + 0.5f) * K, gyc1 = (cy1 + 0.5f) * K;
  const float gy = role ? gyc1 : gyc0;     // this thread's y-corner row

  const unsigned denseOff = P.lv[12].offset;
  unsigned fw2[2][16];   // [x-corner][level], all indices static

  // ---- hashed levels 12..15 first (R7's proven per-thread 2x3 union) ----
  #pragma unroll
  for (int li = 0; li < 4; ++li) {
    const int l = 12 + li;
    const float scale   = P.lv[l].scale;
    const unsigned size = P.lv[l].size;
    const unsigned off  = P.lv[l].offset;
    const unsigned m = size - 1u;          // size == 2^19
    const unsigned* tb = hp + (off - denseOff);

    float px0 = fmaf(gxc0, scale, 0.5f), px1 = fmaf(gxc1, scale, 0.5f);
    float py  = fmaf(gy,   scale, 0.5f);
    float fx0 = floorf(px0), fx1 = floorf(px1), fyv = floorf(py);
    unsigned ux0 = (unsigned)fx0, ux1 = (unsigned)fx1;
    unsigned uy  = (unsigned)fyv;
    bool xs = (ux1 != ux0);                // delta <= 1 grid unit

    unsigned hya = uy * PRIME_Y;
    unsigned hyb = hya + PRIME_Y;

    unsigned h00 = tb[(ux0 ^ hya) & m];
    unsigned h10 = tb[((ux0 + 1u) ^ hya) & m];
    unsigned h01 = tb[(ux0 ^ hyb) & m];
    unsigned h11 = tb[((ux0 + 1u) ^ hyb) & m];
    unsigned h20 = 0u, h21 = 0u;
    if (xs) { h20 = tb[((ux0 + 2u) ^ hya) & m];
              h21 = tb[((ux0 + 2u) ^ hyb) & m]; }

    float frx0 = px0 - fx0, frx1 = px1 - fx1;
    float fry = py - fyv;

    #pragma unroll
    for (int c = 0; c < 2; ++c) {
      bool sx = (c != 0) && xs;
      unsigned e00 = sx ? h10 : h00;
      unsigned e10 = sx ? h20 : h10;
      unsigned e01 = sx ? h11 : h01;
      unsigned e11 = sx ? h21 : h11;
      float frx = c ? frx1 : frx0;
      F2 t00 = bf2unpack(e00), t10 = bf2unpack(e10);
      F2 t01 = bf2unpack(e01), t11 = bf2unpack(e11);
      float wx0 = 1.0f - frx, wx1 = frx;
      float wy0 = 1.0f - fry, wy1 = fry;
      float w00 = wx0 * wy0, w01 = wx0 * wy1;
      float w10 = wx1 * wy0, w11 = wx1 * wy1;
      float fx = w00 * t00.x + w01 * t01.x + w10 * t10.x + w11 * t11.x;
      float fy = w00 * t00.y + w01 * t01.y + w10 * t10.y + w11 * t11.y;
      fw2[c][l] = bf2pack(fx, fy);
    }
  }

  // ---- dense levels 0..11: quad = full bilinear cell per corner ----
  #pragma unroll
  for (int l = 0; l < 12; ++l) {
    const float scale   = P.lv[l].scale;
    const unsigned res  = P.lv[l].res;
    const unsigned off  = P.lv[l].offset;
    const uint4* qt = qtab + off;

    float px0 = fmaf(gxc0, scale, 0.5f), px1 = fmaf(gxc1, scale, 0.5f);
    float py  = fmaf(gy,   scale, 0.5f);
    float fx0 = floorf(px0), fx1 = floorf(px1), fyv = floorf(py);
    unsigned ux0 = (unsigned)fx0, ux1 = (unsigned)fx1;
    unsigned uy  = (unsigned)fyv;
    bool xs = (ux1 != ux0);

    unsigned vA = ux0 + uy * res;        // < size always
    uint4 qA = qt[vA];
    uint4 qB = make_uint4(0u, 0u, 0u, 0u);
    if (xs) qB = qt[vA + 1u];            // adjacent lanes share lines in-wave

    float frx0 = px0 - fx0, frx1 = px1 - fx1;
    float fry = py - fyv;

    #pragma unroll
    for (int c = 0; c < 2; ++c) {
      bool sx = (c != 0) && xs;
      unsigned qx = sx ? qB.x : qA.x;
      unsigned qy = sx ? qB.y : qA.y;
      unsigned qz = sx ? qB.z : qA.z;
      unsigned qw = sx ? qB.w : qA.w;
      float frx = c ? frx1 : frx0;
      F2 t00 = bf2unpack(qx), t10 = bf2unpack(qy);
      F2 t01 = bf2unpack(qz), t11 = bf2unpack(qw);
      float wx0 = 1.0f - frx, wx1 = frx;
      float wy0 = 1.0f - fry, wy1 = fry;
      float w00 = wx0 * wy0, w01 = wx0 * wy1;
      float w10 = wx1 * wy0, w11 = wx1 * wy1;
      float fx = w00 * t00.x + w01 * t01.x + w10 * t10.x + w11 * t11.x;
      float fy = w00 * t00.y + w01 * t01.y + w10 * t10.y + w11 * t11.y;
      fw2[c][l] = bf2pack(fx, fy);
    }
  }

  __syncthreads();   // W0/W1 staging visible to all waves

  f32x4 outacc[4];
  #pragma unroll
  for (int b = 0; b < 4; ++b) outacc[b] = (f32x4){0.f, 0.f, 0.f, 0.f};

  // ---- 2 MFMA rounds: round rr = x-corner rr; F row = lane ----
  // (R6's proven H-half MLP inner structure, verbatim.)
  #pragma unroll
  for (int rr = 0; rr < 2; ++rr) {
    *(uint4*)(sFH + L * 80 +  0) =
        make_uint4(fw2[rr][0],  fw2[rr][1],  fw2[rr][2],  fw2[rr][3]);
    *(uint4*)(sFH + L * 80 + 16) =
        make_uint4(fw2[rr][4],  fw2[rr][5],  fw2[rr][6],  fw2[rr][7]);
    *(uint4*)(sFH + L * 80 + 32) =
        make_uint4(fw2[rr][8],  fw2[rr][9],  fw2[rr][10], fw2[rr][11]);
    *(uint4*)(sFH + L * 80 + 48) =
        make_uint4(fw2[rr][12], fw2[rr][13], fw2[rr][14], fw2[rr][15]);

    // F tiles into regs; region is then reused for the H-halves
    short8 bfr[4];
    #pragma unroll
    for (int b = 0; b < 4; ++b)
      bfr[b] = *(const short8*)(sFH + (16 * b + r16) * 80 + g * 16);

    f32x4 oacc[4];
    #pragma unroll
    for (int b = 0; b < 4; ++b) oacc[b] = (f32x4){0.f, 0.f, 0.f, 0.f};

    #pragma unroll
    for (int h = 0; h < 2; ++h) {
      // layer 1, half h: a in {2h, 2h+1} -> H cols [32h, 32h+32)
      #pragma unroll
      for (int ai = 0; ai < 2; ++ai) {
        const int a = 2 * h + ai;
        short8 afr = *(const short8*)(smem + (16 * a + r16) * 80 + g * 16);
        f32x4 acc[4];
        #pragma unroll
        for (int b = 0; b < 4; ++b) acc[b] = (f32x4){0.f, 0.f, 0.f, 0.f};
        #pragma unroll
        for (int b = 0; b < 4; ++b)
          acc[b] = __builtin_amdgcn_mfma_f32_16x16x32_bf16(afr, bfr[b],
                                                           acc[b], 0, 0, 0);
        #pragma unroll
        for (int b = 0; b < 4; ++b) {
          f32x4 hh = acc[b];
          float h0 = fmaxf(hh.x, 0.f), h1 = fmaxf(hh.y, 0.f);
          float h2 = fmaxf(hh.z, 0.f), h3 = fmaxf(hh.w, 0.f);
          const int row = 16 * b + r16;
          *(uint2*)(sFH + row * 64 +
                    ((ai * 32 + g * 8) ^ ((row & 3) << 4))) =
              make_uint2(bf2pack(h0, h1), bf2pack(h2, h3));
        }
      }
      // layer 2, k-slice h
      short8 a2 = *(const short8*)(smem + 5120 + r16 * 128 +
                                   ((h * 64 + g * 16) ^ ((r16 & 7) << 4)));
      #pragma unroll
      for (int b = 0; b < 4; ++b) {
        const int row = 16 * b + r16;
        short8 b2 = *(const short8*)(sFH + row * 64 +
                                     ((g * 16) ^ ((row & 3) << 4)));
        oacc[b] = __builtin_amdgcn_mfma_f32_16x16x32_bf16(a2, b2, oacc[b],
                                                          0, 0, 0);
      }
    }

    // corner blend: row m = 16b+r16 is corner (x_rr, y_{m&1}) of point m>>1.
    // Each lane's wcr = weight of ITS corner-instance for this round.
    float wcr = (rr ? u : 1.0f - u) * (role ? v : 1.0f - v);
    #pragma unroll
    for (int b = 0; b < 4; ++b) {
      float wcm = __shfl(wcr, 16 * b + r16, 64);
      outacc[b].x = fmaf(wcm, oacc[b].x, outacc[b].x);
      outacc[b].y = fmaf(wcm, oacc[b].y, outacc[b].y);
      outacc[b].z = fmaf(wcm, oacc[b].z, outacc[b].z);
      outacc[b].w = fmaf(wcm, oacc[b].w, outacc[b].w);
    }
  }

  // ---- cross-pair reduce (rows m and m^1 are the two y-roles) + store ----
  #pragma unroll
  for (int b = 0; b < 4; ++b) {
    outacc[b].x += __shfl_xor(outacc[b].x, 1, 64);
    outacc[b].y += __shfl_xor(outacc[b].y, 1, 64);
    outacc[b].z += __shfl_xor(outacc[b].z, 1, 64);
    outacc[b].w += __shfl_xor(outacc[b].w, 1, 64);
  }
  if ((r16 & 1) == 0 && g < 2) {
    #pragma unroll
    for (int b = 0; b < 4; ++b) {
      int po = blockIdx.x * 128 + w * 32 + ((16 * b + r16) >> 1);
      *(f32x4*)(out + (size_t)po * 8 + 4 * g) = outacc[b];
    }
  }
}

// ============================================================================
// Fallback kernel (old structure, 4 threads/point): TBF=1 packed / TBF=0 fp32
// ============================================================================
template <int TBF>
__global__ __launch_bounds__(256, 4) void plane_fwd(
    const F2* __restrict__ xy,
    const F2* __restrict__ table,
    const unsigned* __restrict__ tbf16,
    const float* __restrict__ w0g,
    const float* __restrict__ w1g,
    const int* __restrict__ boundp,
    float* __restrict__ out,
    EncParams P)
{
  __shared__ __align__(16) char smem[SMEM_FB];
  const int t = threadIdx.x;
  const int L = t & 63;
  const int w = t >> 6;
  const int r16 = L & 15;
  const int g = L >> 4;

  {
    const float4* s = (const float4*)w0g;
    float4 a = s[t * 2], b = s[t * 2 + 1];
    uint4 pk = make_uint4(bf2pack(a.x, a.y), bf2pack(a.z, a.w),
                          bf2pack(b.x, b.y), bf2pack(b.z, b.w));
    *(uint4*)(smem + (t >> 2) * 80 + (t & 3) * 16) = pk;
  }
  {
    int row = t >> 4;
    int colb = (t & 15) * 8;
    float c0 = 0.f, c1 = 0.f, c2 = 0.f, c3 = 0.f;
    if (row < 8) {
      float4 wv = *(const float4*)(w1g + row * 64 + (t & 15) * 4);
      c0 = wv.x; c1 = wv.y; c2 = wv.z; c3 = wv.w;
    }
    *(uint2*)(smem + 5120 + row * 128 + (colb ^ ((row & 7) << 4))) =
        make_uint2(bf2pack(c0, c1), bf2pack(c2, c3));
  }

  char* sFH = smem + 7168 + w * 8192;

  const int gid = blockIdx.x * 256 + t;
  const int p = gid >> 2;
  const int c = t & 3;
  F2 pxy = xy[p];

  int braw = boundp[0];
  float bf = (braw > 0x00800000) ? __int_as_float(braw) : (float)braw;
  float inv2b = 0.5f / bf;
  float xn = (pxy.x + bf) * inv2b;
  float yn = (pxy.y + bf) * inv2b;

  float cx  = fminf(fmaxf(xn * 2048.0f - 0.5f, 0.0f), 2047.0f);
  float cyv = fminf(fmaxf(yn * 2048.0f - 0.5f, 0.0f), 2047.0f);
  float cx0 = floorf(cx), cy0 = floorf(cyv);
  float u = cx - cx0, v = cyv - cy0;
  float cx1 = fminf(cx0 + 1.0f, 2047.0f);
  float cy1 = fminf(cy0 + 1.0f, 2047.0f);

  const float cxc = (c & 1) ? cx1 : cx0;
  const float cyc = (c & 2) ? cy1 : cy0;
  const float wc = ((c & 1) ? u : 1.0f - u) * ((c & 2) ? v : 1.0f - v);

  const float K = 1.0f / 2048.0f;
  const float gx = (cxc + 0.5f) * K;
  const float gy = (cyc + 0.5f) * K;

  unsigned fw[16];

  #pragma unroll
  for (int lidx = 0; lidx < 16; ++lidx) {
    const int l = (lidx < 4) ? (12 + lidx) : (lidx - 4);
    const float scale   = P.lv[l].scale;
    const unsigned res  = P.lv[l].res;
    const unsigned size = P.lv[l].size;
    const unsigned off  = P.lv[l].offset;
    const bool hashed = (res * res) > size;

    float px = fmaf(gx, scale, 0.5f);
    float pgx = floorf(px);
    float frx = px - pgx;
    unsigned ux = (unsigned)pgx;

    float py = fmaf(gy, scale, 0.5f);
    float pgy = floorf(py);
    float fry = py - pgy;
    unsigned uy = (unsigned)pgy;

    unsigned i00, i01, i10, i11;
    if (hashed) {
      const unsigned m = size - 1u;
      unsigned hy0 = uy * PRIME_Y;
      unsigned hy1 = hy0 + PRIME_Y;
      i00 = (ux ^ hy0) & m;
      i01 = (ux ^ hy1) & m;
      i10 = ((ux + 1u) ^ hy0) & m;
      i11 = ((ux + 1u) ^ hy1) & m;
    } else {
      unsigned b0 = uy * res, b1 = b0 + res;
      unsigned q00 = ux + b0,      q01 = ux + b1;
      unsigned q10 = ux + 1u + b0, q11 = ux + 1u + b1;
      i00 = q00 >= size ? q00 - size : q00;
      i01 = q01 >= size ? q01 - size : q01;
      i10 = q10 >= size ? q10 - size : q10;
      i11 = q11 >= size ? q11 - size : q11;
    }

    F2 t00, t01, t10, t11;
    if (TBF == 1) {
      const unsigned* tb = tbf16 + off;
      t00 = bf2unpack(tb[i00]);
      t01 = bf2unpack(tb[i01]);
      t10 = bf2unpack(tb[i10]);
      t11 = bf2unpack(tb[i11]);
    } else {
      const F2* tabp = table + off;
      t00 = tabp[i00]; t01 = tabp[i01]; t10 = tabp[i10]; t11 = tabp[i11];
    }

    float wx0 = 1.0f - frx, wx1 = frx;
    float wy0 = 1.0f - fry, wy1 = fry;
    float w00 = wx0 * wy0, w01 = wx0 * wy1, w10 = wx1 * wy0, w11 = wx1 * wy1;
    float fx = w00 * t00.x + w01 * t01.x + w10 * t10.x + w11 * t11.x;
    float fy = w00 * t00.y + w01 * t01.y + w10 * t10.y + w11 * t11.y;
    fw[l] = bf2pack(fx, fy);
  }

  *(uint4*)(sFH + L * 80 +  0) = make_uint4(fw[0],  fw[1],  fw[2],  fw[3]);
  *(uint4*)(sFH + L * 80 + 16) = make_uint4(fw[4],  fw[5],  fw[6],  fw[7]);
  *(uint4*)(sFH + L * 80 + 32) = make_uint4(fw[8],  fw[9],  fw[10], fw[11]);
  *(uint4*)(sFH + L * 80 + 48) = make_uint4(fw[12], fw[13], fw[14], fw[15]);

  __syncthreads();

  short8 afr[4], bfr[4];
  #pragma unroll
  for (int b = 0; b < 4; ++b)
    bfr[b] = *(const short8*)(sFH + (16 * b + r16) * 80 + g * 16);
  #pragma unroll
  for (int a = 0; a < 4; ++a)
    afr[a] = *(const short8*)(smem + (16 * a + r16) * 80 + g * 16);

  f32x4 acc[4][4];
  #pragma unroll
  for (int a = 0; a < 4; ++a)
    #pragma unroll
    for (int b = 0; b < 4; ++b)
      acc[a][b] = (f32x4){0.f, 0.f, 0.f, 0.f};

  #pragma unroll
  for (int a = 0; a < 4; ++a)
    #pragma unroll
    for (int b = 0; b < 4; ++b)
      acc[a][b] = __builtin_amdgcn_mfma_f32_16x16x32_bf16(
          afr[a], bfr[b], acc[a][b], 0, 0, 0);

  #pragma unroll
  for (int a = 0; a < 4; ++a)
    #pragma unroll
    for (int b = 0; b < 4; ++b) {
      f32x4 h = acc[a][b];
      float h0 = fmaxf(h.x, 0.f), h1 = fmaxf(h.y, 0.f);
      float h2 = fmaxf(h.z, 0.f), h3 = fmaxf(h.w, 0.f);
      *(uint2*)(sFH + (16 * b + r16) * 128 +
                ((a * 32 + g * 8) ^ ((r16 & 7) << 4))) =
          make_uint2(bf2pack(h0, h1), bf2pack(h2, h3));
    }

  f32x4 oacc[4];
  #pragma unroll
  for (int b = 0; b < 4; ++b) oacc[b] = (f32x4){0.f, 0.f, 0.f, 0.f};

  #pragma unroll
  for (int ks = 0; ks < 2; ++ks) {
    short8 a2 = *(const short8*)(smem + 5120 + r16 * 128 +
                                 ((ks * 64 + g * 16) ^ ((r16 & 7) << 4)));
    #pragma unroll
    for (int b = 0; b < 4; ++b) {
      short8 b2 = *(const short8*)(sFH + (16 * b + r16) * 128 +
                                   ((ks * 64 + g * 16) ^ ((r16 & 7) << 4)));
      oacc[b] = __builtin_amdgcn_mfma_f32_16x16x32_bf16(a2, b2, oacc[b], 0, 0, 0);
    }
  }

  #pragma unroll
  for (int b = 0; b < 4; ++b) {
    float wcm = __shfl(wc, 16 * b + r16, 64);
    float v0 = oacc[b].x * wcm;
    float v1 = oacc[b].y * wcm;
    float v2 = oacc[b].z * wcm;
    float v3 = oacc[b].w * wcm;
    v0 += __shfl_xor(v0, 1, 64); v0 += __shfl_xor(v0, 2, 64);
    v1 += __shfl_xor(v1, 1, 64); v1 += __shfl_xor(v1, 2, 64);
    v2 += __shfl_xor(v2, 1, 64); v2 += __shfl_xor(v2, 2, 64);
    v3 += __shfl_xor(v3, 1, 64); v3 += __shfl_xor(v3, 2, 64);
    if ((L & 3) == 0 && g < 2) {
      int pt = blockIdx.x * 64 + w * 16 + 4 * b + (r16 >> 2);
      *(f32x4*)(out + (size_t)pt * 8 + 4 * g) = (f32x4){v0, v1, v2, v3};
    }
  }
}

extern "C" void kernel_launch(void* const* d_in, const int* in_sizes, int n_in,
                              void* d_out, int out_size, void* d_ws, size_t ws_size,
                              hipStream_t stream) {
  EncParams P;
  double b = exp2(log2(2048.0 / 16.0) / 15.0);
  unsigned off = 0;
  for (int l = 0; l < 16; ++l) {
    double s = 16.0 * pow(b, (double)l) - 1.0;
    int r = (int)ceil(s) + 1;
    unsigned p = (unsigned)(r * r);
    if (p > 524288u) p = 524288u;
    p = (p + 7u) / 8u * 8u;
    P.lv[l].scale = (float)s;
    P.lv[l].res = (unsigned)r;
    P.lv[l].size = p;
    P.lv[l].offset = off;
    off += p;
  }
  const int total_params = (int)off;

  int hstart = 16;
  for (int l = 0; l < 16; ++l) {
    unsigned long long rr = (unsigned long long)P.lv[l].res * P.lv[l].res;
    if (rr > P.lv[l].size) { hstart = l; break; }
  }
  const unsigned denseTotal = (hstart < 16) ? P.lv[hstart].offset
                                            : (unsigned)total_params;
  const size_t quadBytes = (size_t)denseTotal * 16;
  const size_t hashBytes = (size_t)((unsigned)total_params - denseTotal) * 4;
  const size_t packBytes = (size_t)total_params * 4;

  const int N = in_sizes[0] / 2;  // xy is [N,2]
  const F2* xy = (const F2*)d_in[0];
  const F2* table = (const F2*)d_in[1];
  const float* w0g = (const float*)d_in[2];
  const float* w1g = (const float*)d_in[3];
  const int* bp = (const int*)d_in[4];
  float* outp = (float*)d_out;

  if (hstart == 12 && (N & 127) == 0 && ws_size >= quadBytes + hashBytes) {
    uint4* quad = (uint4*)d_ws;
    unsigned* hp = (unsigned*)((char*)d_ws + quadBytes);
    prep3<<<(total_params + 255) / 256, 256, 0, stream>>>(
        table, quad, hp, P, denseTotal, (unsigned)total_params);
    plane_fwd1<<<N / 128, 256, 0, stream>>>(xy, quad, hp, w0g, w1g, bp,
                                            outp, P);
  } else if (ws_size >= packBytes) {
    unsigned* tbf = (unsigned*)d_ws;
    cvt_table<<<(total_params + 255) / 256, 256, 0, stream>>>(table, tbf,
                                                              total_params);
    plane_fwd<1><<<N / 64, 256, 0, stream>>>(xy, table, tbf, w0g, w1g, bp,
                                             outp, P);
  } else {
    plane_fwd<0><<<N / 64, 256, 0, stream>>>(xy, table, nullptr, w0g, w1g, bp,
                                             outp, P);
  }
}

// Round 10
// 249.104 us; speedup vs baseline: 1.4310x; 1.0764x over previous
//
#include <hip/hip_runtime.h>
#include <math.h>

#define PRIME_Y 2654435761u

struct LevelParams { float scale; unsigned res; unsigned size; unsigned offset; };
struct EncParams { LevelParams lv[16]; };

typedef __attribute__((ext_vector_type(8))) short short8;
typedef __attribute__((ext_vector_type(4))) float f32x4;

struct alignas(8) F2 { float x, y; };

// fp32 pair -> packed bf16 (RNE), low = a, high = b.
__device__ inline unsigned bf2pack(float a, float b) {
  unsigned r;
  asm("v_cvt_pk_bf16_f32 %0, %1, %2" : "=v"(r) : "v"(a), "v"(b));
  return r;
}
__device__ inline F2 bf2unpack(unsigned u) {
  F2 r;
  r.x = __uint_as_float(u << 16);
  r.y = __uint_as_float(u & 0xFFFF0000u);
  return r;
}

// Fallback: full table fp32 [n][2] -> packed bf16 [n]
__global__ __launch_bounds__(256) void cvt_table(const F2* __restrict__ in,
                                                 unsigned* __restrict__ outb,
                                                 int n) {
  int i = blockIdx.x * 256 + threadIdx.x;
  if (i < n) {
    F2 v = in[i];
    outb[i] = bf2pack(v.x, v.y);
  }
}

// Prep. Dense [0,denseTotal): quad[v] = packed-bf16
// (T[v], T[(v+1)%sz], T[(v+res)%sz], T[(v+res+1)%sz]) -- one 16B load serves a
// full bilinear cell, wraps folded at build (exact reference semantics).
// Hashed [denseTotal,total): packed bf16 (4B), stored at hp[i-denseTotal].
__global__ __launch_bounds__(256) void prep3(
    const F2* __restrict__ in, uint4* __restrict__ quad,
    unsigned* __restrict__ hp, EncParams P, unsigned denseTotal,
    unsigned total) {
  unsigned i = blockIdx.x * 256 + threadIdx.x;
  if (i >= total) return;
  if (i >= denseTotal) {
    F2 a = in[i];
    hp[i - denseTotal] = bf2pack(a.x, a.y);
    return;
  }
  unsigned off = 0, size = 0, res = 0;
  #pragma unroll
  for (int l = 0; l < 12; ++l)
    if (i >= P.lv[l].offset) {
      off = P.lv[l].offset; size = P.lv[l].size; res = P.lv[l].res;
    }
  unsigned j = i - off;
  unsigned j1 = j + 1u;        if (j1 >= size) j1 -= size;
  unsigned j2 = j + res;       if (j2 >= size) j2 -= size;
  unsigned j3 = j + res + 1u;  if (j3 >= size) j3 -= size;
  F2 a0 = in[off + j],  a1 = in[off + j1];
  F2 a2 = in[off + j2], a3 = in[off + j3];
  quad[i] = make_uint4(bf2pack(a0.x, a0.y), bf2pack(a1.x, a1.y),
                       bf2pack(a2.x, a2.y), bf2pack(a3.x, a3.y));
}

// Primary-kernel LDS map (bytes):
//   [0,5120)     sW0  bf16 [64 rows][32] row stride 80
//   [5120,7168)  sW1  bf16 [16 rows][64] stride 128, XOR-swizzled (row&7)<<4
//   [7168,27648) per-wave region, 5120 B each:
//                  F bf16 [64][32] stride 80 (consumed into regs), then
//                  reluH HALF [64 m][32 j] stride 80 (R10: was 64 -- the
//                  stride-64 layout cost +10.6M bank-conflict cycles in R9;
//                  stride 80 is the proven conflict-free F pattern)
// 27648 -> LDS cap 5 blocks/CU (R9: occupancy 52% validated).
// R9 lesson: pair-split occupancy worked (+25%) but per-thread hashed rows
// were ~60% redundant (+42% FETCH). R10 shares them: each thread loads ONE
// row of the 3-row union; shfl_xor(,1) exchanges -- hashed slots back to
// R4's level at R9's occupancy.
#define SMEM_BYTES 27648
#define SMEM_FB 39936   // fallback kernel keeps the old map

// ============================================================================
// Primary kernel: 2 threads per point. Lane L: point L>>1, role = L&1.
// Hashed levels: shared base row uyB (both threads agree); role0 loads row B
// (+ row B+2 if ys), role1 loads row B+1; shfl_xor(,1) delivers each thread
// its 2-row window. Dense: per-role quads (same-address dup merges in TA).
// MLP: 2 MFMA rounds, blend via shfl(wcr,row), cross-pair shfl_xor reduce.
// ============================================================================
__global__ __launch_bounds__(256, 4) void plane_fwd1(
    const F2* __restrict__ xy,
    const uint4* __restrict__ qtab,     // dense quads, absolute entry index
    const unsigned* __restrict__ hp,    // hashed packed, base = denseTotal
    const float* __restrict__ w0g,
    const float* __restrict__ w1g,
    const int* __restrict__ boundp,
    float* __restrict__ out,
    EncParams P)
{
  __shared__ __align__(16) char smem[SMEM_BYTES];
  const int t = threadIdx.x;
  const int L = t & 63;
  const int w = t >> 6;
  const int r16 = L & 15;
  const int g = L >> 4;
  const int role = L & 1;

  // ---- stage W0 (bf16, stride 80) ----
  {
    const float4* s = (const float4*)w0g;
    float4 a = s[t * 2], b = s[t * 2 + 1];
    uint4 pk = make_uint4(bf2pack(a.x, a.y), bf2pack(a.z, a.w),
                          bf2pack(b.x, b.y), bf2pack(b.z, b.w));
    *(uint4*)(smem + (t >> 2) * 80 + (t & 3) * 16) = pk;
  }
  // ---- stage W1 (bf16, [16][64] stride 128 swizzled, rows 8..15 = 0) ----
  {
    int row = t >> 4;
    int colb = (t & 15) * 8;
    float c0 = 0.f, c1 = 0.f, c2 = 0.f, c3 = 0.f;
    if (row < 8) {
      float4 wv = *(const float4*)(w1g + row * 64 + (t & 15) * 4);
      c0 = wv.x; c1 = wv.y; c2 = wv.z; c3 = wv.w;
    }
    *(uint2*)(smem + 5120 + row * 128 + (colb ^ ((row & 7) << 4))) =
        make_uint2(bf2pack(c0, c1), bf2pack(c2, c3));
  }

  char* sFH = smem + 7168 + w * 5120;

  // ---- per-point setup (both threads of a pair compute identically) ----
  const int pt = blockIdx.x * 128 + w * 32 + (L >> 1);
  F2 pxy = xy[pt];

  int braw = boundp[0];
  float bf = (braw > 0x00800000) ? __int_as_float(braw) : (float)braw;
  float inv2b = 0.5f / bf;
  float xn = (pxy.x + bf) * inv2b;
  float yn = (pxy.y + bf) * inv2b;

  float cx  = fminf(fmaxf(xn * 2048.0f - 0.5f, 0.0f), 2047.0f);
  float cyv = fminf(fmaxf(yn * 2048.0f - 0.5f, 0.0f), 2047.0f);
  float cx0 = floorf(cx), cy0 = floorf(cyv);
  float u = cx - cx0, v = cyv - cy0;
  float cx1 = fminf(cx0 + 1.0f, 2047.0f);
  float cy1 = fminf(cy0 + 1.0f, 2047.0f);

  const float K = 1.0f / 2048.0f;
  const float gxc0 = (cx0 + 0.5f) * K, gxc1 = (cx1 + 0.5f) * K;
  const float gyc0 = (cy0 + 0.5f) * K, gyc1 = (cy1 + 0.5f) * K;
  const float gy = role ? gyc1 : gyc0;     // this thread's y-corner row

  const unsigned denseOff = P.lv[12].offset;
  unsigned fw2[2][16];   // [x-corner][level], all indices static

  // ---- hashed levels 12..15: pair-shared 3-row union via shfl_xor ----
  #pragma unroll
  for (int li = 0; li < 4; ++li) {
    const int l = 12 + li;
    const float scale   = P.lv[l].scale;
    const unsigned size = P.lv[l].size;
    const unsigned off  = P.lv[l].offset;
    const unsigned m = size - 1u;          // size == 2^19
    const unsigned* tb = hp + (off - denseOff);

    float px0 = fmaf(gxc0, scale, 0.5f), px1 = fmaf(gxc1, scale, 0.5f);
    float py0 = fmaf(gyc0, scale, 0.5f), py1 = fmaf(gyc1, scale, 0.5f);
    float fx0 = floorf(px0), fx1 = floorf(px1);
    float fy0 = floorf(py0), fy1 = floorf(py1);
    unsigned ux0 = (unsigned)fx0, ux1 = (unsigned)fx1;
    unsigned uyB = (unsigned)fy0, uy1 = (unsigned)fy1;
    bool xs = (ux1 != ux0), ys = (uy1 != uyB);   // shared across the pair

    unsigned hB = uyB * PRIME_Y;
    // own row: role0 -> B, role1 -> B+1 (single full-lane instruction)
    unsigned hOwn = hB + (role ? PRIME_Y : 0u);
    unsigned o0 = tb[(ux0 ^ hOwn) & m];
    unsigned o1 = tb[((ux0 + 1u) ^ hOwn) & m];
    unsigned o2 = 0u;
    if (xs) o2 = tb[((ux0 + 2u) ^ hOwn) & m];
    // extra row B+2: only role0 when ys (role1's partner need)
    unsigned x0 = 0u, x1 = 0u, x2 = 0u;
    if (!role && ys) {
      unsigned hX = hB + 2u * PRIME_Y;
      x0 = tb[(ux0 ^ hX) & m];
      x1 = tb[((ux0 + 1u) ^ hX) & m];
      if (xs) x2 = tb[((ux0 + 2u) ^ hX) & m];
    }
    // exchange: role0 sends row (ys ? B+2 : B); role1 sends row B+1
    bool sendX = (!role) && ys;
    unsigned s0 = sendX ? x0 : o0;
    unsigned s1 = sendX ? x1 : o1;
    unsigned s2 = sendX ? x2 : o2;
    unsigned r0 = __shfl_xor(s0, 1, 64);
    unsigned r1 = __shfl_xor(s1, 1, 64);
    unsigned r2 = __shfl_xor(s2, 1, 64);
    // window rows {uyOwn, uyOwn+1}:
    //   role0:        lo = own(B),    hi = recv(B+1)
    //   role1, !ys:   lo = recv(B),   hi = own(B+1)
    //   role1,  ys:   lo = own(B+1),  hi = recv(B+2)
    bool swapR = role && !ys;
    unsigned lo0 = swapR ? r0 : o0, hi0 = swapR ? o0 : r0;
    unsigned lo1 = swapR ? r1 : o1, hi1 = swapR ? o1 : r1;
    unsigned lo2 = swapR ? r2 : o2, hi2 = swapR ? o2 : r2;

    float fry = role ? (py1 - fy1) : (py0 - fy0);
    float frx0v = px0 - fx0, frx1v = px1 - fx1;

    #pragma unroll
    for (int c = 0; c < 2; ++c) {
      bool sx = (c != 0) && xs;
      unsigned e00 = sx ? lo1 : lo0;
      unsigned e10 = sx ? lo2 : lo1;
      unsigned e01 = sx ? hi1 : hi0;
      unsigned e11 = sx ? hi2 : hi1;
      float frx = c ? frx1v : frx0v;
      F2 t00 = bf2unpack(e00), t10 = bf2unpack(e10);
      F2 t01 = bf2unpack(e01), t11 = bf2unpack(e11);
      float wx0 = 1.0f - frx, wx1 = frx;
      float wy0 = 1.0f - fry, wy1 = fry;
      float w00 = wx0 * wy0, w01 = wx0 * wy1;
      float w10 = wx1 * wy0, w11 = wx1 * wy1;
      float fx = w00 * t00.x + w01 * t01.x + w10 * t10.x + w11 * t11.x;
      float fy = w00 * t00.y + w01 * t01.y + w10 * t10.y + w11 * t11.y;
      fw2[c][l] = bf2pack(fx, fy);
    }
  }

  // ---- dense levels 0..11: quad = full bilinear cell per corner ----
  // Same-address pair duplicates merge in the TA; no exchange needed.
  #pragma unroll
  for (int l = 0; l < 12; ++l) {
    const float scale   = P.lv[l].scale;
    const unsigned res  = P.lv[l].res;
    const unsigned off  = P.lv[l].offset;
    const uint4* qt = qtab + off;

    float px0 = fmaf(gxc0, scale, 0.5f), px1 = fmaf(gxc1, scale, 0.5f);
    float py  = fmaf(gy,   scale, 0.5f);
    float fx0 = floorf(px0), fx1 = floorf(px1), fyv = floorf(py);
    unsigned ux0 = (unsigned)fx0, ux1 = (unsigned)fx1;
    unsigned uy  = (unsigned)fyv;
    bool xs = (ux1 != ux0);

    unsigned vA = ux0 + uy * res;        // < size always
    uint4 qA = qt[vA];
    uint4 qB = make_uint4(0u, 0u, 0u, 0u);
    if (xs) qB = qt[vA + 1u];

    float frx0 = px0 - fx0, frx1 = px1 - fx1;
    float fry = py - fyv;

    #pragma unroll
    for (int c = 0; c < 2; ++c) {
      bool sx = (c != 0) && xs;
      unsigned qx = sx ? qB.x : qA.x;
      unsigned qy = sx ? qB.y : qA.y;
      unsigned qz = sx ? qB.z : qA.z;
      unsigned qw = sx ? qB.w : qA.w;
      float frx = c ? frx1 : frx0;
      F2 t00 = bf2unpack(qx), t10 = bf2unpack(qy);
      F2 t01 = bf2unpack(qz), t11 = bf2unpack(qw);
      float wx0 = 1.0f - frx, wx1 = frx;
      float wy0 = 1.0f - fry, wy1 = fry;
      float w00 = wx0 * wy0, w01 = wx0 * wy1;
      float w10 = wx1 * wy0, w11 = wx1 * wy1;
      float fx = w00 * t00.x + w01 * t01.x + w10 * t10.x + w11 * t11.x;
      float fy = w00 * t00.y + w01 * t01.y + w10 * t10.y + w11 * t11.y;
      fw2[c][l] = bf2pack(fx, fy);
    }
  }

  __syncthreads();   // W0/W1 staging visible to all waves

  f32x4 outacc[4];
  #pragma unroll
  for (int b = 0; b < 4; ++b) outacc[b] = (f32x4){0.f, 0.f, 0.f, 0.f};

  // ---- 2 MFMA rounds: round rr = x-corner rr; F row = lane ----
  #pragma unroll
  for (int rr = 0; rr < 2; ++rr) {
    *(uint4*)(sFH + L * 80 +  0) =
        make_uint4(fw2[rr][0],  fw2[rr][1],  fw2[rr][2],  fw2[rr][3]);
    *(uint4*)(sFH + L * 80 + 16) =
        make_uint4(fw2[rr][4],  fw2[rr][5],  fw2[rr][6],  fw2[rr][7]);
    *(uint4*)(sFH + L * 80 + 32) =
        make_uint4(fw2[rr][8],  fw2[rr][9],  fw2[rr][10], fw2[rr][11]);
    *(uint4*)(sFH + L * 80 + 48) =
        make_uint4(fw2[rr][12], fw2[rr][13], fw2[rr][14], fw2[rr][15]);

    // F tiles into regs; region is then reused for the H-halves
    short8 bfr[4];
    #pragma unroll
    for (int b = 0; b < 4; ++b)
      bfr[b] = *(const short8*)(sFH + (16 * b + r16) * 80 + g * 16);

    f32x4 oacc[4];
    #pragma unroll
    for (int b = 0; b < 4; ++b) oacc[b] = (f32x4){0.f, 0.f, 0.f, 0.f};

    #pragma unroll
    for (int h = 0; h < 2; ++h) {
      // layer 1, half h: a in {2h, 2h+1} -> H cols [32h, 32h+32)
      #pragma unroll
      for (int ai = 0; ai < 2; ++ai) {
        const int a = 2 * h + ai;
        short8 afr = *(const short8*)(smem + (16 * a + r16) * 80 + g * 16);
        f32x4 acc[4];
        #pragma unroll
        for (int b = 0; b < 4; ++b) acc[b] = (f32x4){0.f, 0.f, 0.f, 0.f};
        #pragma unroll
        for (int b = 0; b < 4; ++b)
          acc[b] = __builtin_amdgcn_mfma_f32_16x16x32_bf16(afr, bfr[b],
                                                           acc[b], 0, 0, 0);
        #pragma unroll
        for (int b = 0; b < 4; ++b) {
          f32x4 hh = acc[b];
          float h0 = fmaxf(hh.x, 0.f), h1 = fmaxf(hh.y, 0.f);
          float h2 = fmaxf(hh.z, 0.f), h3 = fmaxf(hh.w, 0.f);
          const int row = 16 * b + r16;
          *(uint2*)(sFH + row * 80 + ai * 32 + g * 8) =
              make_uint2(bf2pack(h0, h1), bf2pack(h2, h3));
        }
      }
      // layer 2, k-slice h
      short8 a2 = *(const short8*)(smem + 5120 + r16 * 128 +
                                   ((h * 64 + g * 16) ^ ((r16 & 7) << 4)));
      #pragma unroll
      for (int b = 0; b < 4; ++b) {
        const int row = 16 * b + r16;
        short8 b2 = *(const short8*)(sFH + row * 80 + g * 16);
        oacc[b] = __builtin_amdgcn_mfma_f32_16x16x32_bf16(a2, b2, oacc[b],
                                                          0, 0, 0);
      }
    }

    // corner blend: row m = 16b+r16 is corner (x_rr, y_{m&1}) of point m>>1.
    float wcr = (rr ? u : 1.0f - u) * (role ? v : 1.0f - v);
    #pragma unroll
    for (int b = 0; b < 4; ++b) {
      float wcm = __shfl(wcr, 16 * b + r16, 64);
      outacc[b].x = fmaf(wcm, oacc[b].x, outacc[b].x);
      outacc[b].y = fmaf(wcm, oacc[b].y, outacc[b].y);
      outacc[b].z = fmaf(wcm, oacc[b].z, outacc[b].z);
      outacc[b].w = fmaf(wcm, oacc[b].w, outacc[b].w);
    }
  }

  // ---- cross-pair reduce (rows m and m^1 are the two y-roles) + store ----
  #pragma unroll
  for (int b = 0; b < 4; ++b) {
    outacc[b].x += __shfl_xor(outacc[b].x, 1, 64);
    outacc[b].y += __shfl_xor(outacc[b].y, 1, 64);
    outacc[b].z += __shfl_xor(outacc[b].z, 1, 64);
    outacc[b].w += __shfl_xor(outacc[b].w, 1, 64);
  }
  if ((r16 & 1) == 0 && g < 2) {
    #pragma unroll
    for (int b = 0; b < 4; ++b) {
      int po = blockIdx.x * 128 + w * 32 + ((16 * b + r16) >> 1);
      *(f32x4*)(out + (size_t)po * 8 + 4 * g) = outacc[b];
    }
  }
}

// ============================================================================
// Fallback kernel (old structure, 4 threads/point): TBF=1 packed / TBF=0 fp32
// ============================================================================
template <int TBF>
__global__ __launch_bounds__(256, 4) void plane_fwd(
    const F2* __restrict__ xy,
    const F2* __restrict__ table,
    const unsigned* __restrict__ tbf16,
    const float* __restrict__ w0g,
    const float* __restrict__ w1g,
    const int* __restrict__ boundp,
    float* __restrict__ out,
    EncParams P)
{
  __shared__ __align__(16) char smem[SMEM_FB];
  const int t = threadIdx.x;
  const int L = t & 63;
  const int w = t >> 6;
  const int r16 = L & 15;
  const int g = L >> 4;

  {
    const float4* s = (const float4*)w0g;
    float4 a = s[t * 2], b = s[t * 2 + 1];
    uint4 pk = make_uint4(bf2pack(a.x, a.y), bf2pack(a.z, a.w),
                          bf2pack(b.x, b.y), bf2pack(b.z, b.w));
    *(uint4*)(smem + (t >> 2) * 80 + (t & 3) * 16) = pk;
  }
  {
    int row = t >> 4;
    int colb = (t & 15) * 8;
    float c0 = 0.f, c1 = 0.f, c2 = 0.f, c3 = 0.f;
    if (row < 8) {
      float4 wv = *(const float4*)(w1g + row * 64 + (t & 15) * 4);
      c0 = wv.x; c1 = wv.y; c2 = wv.z; c3 = wv.w;
    }
    *(uint2*)(smem + 5120 + row * 128 + (colb ^ ((row & 7) << 4))) =
        make_uint2(bf2pack(c0, c1), bf2pack(c2, c3));
  }

  char* sFH = smem + 7168 + w * 8192;

  const int gid = blockIdx.x * 256 + t;
  const int p = gid >> 2;
  const int c = t & 3;
  F2 pxy = xy[p];

  int braw = boundp[0];
  float bf = (braw > 0x00800000) ? __int_as_float(braw) : (float)braw;
  float inv2b = 0.5f / bf;
  float xn = (pxy.x + bf) * inv2b;
  float yn = (pxy.y + bf) * inv2b;

  float cx  = fminf(fmaxf(xn * 2048.0f - 0.5f, 0.0f), 2047.0f);
  float cyv = fminf(fmaxf(yn * 2048.0f - 0.5f, 0.0f), 2047.0f);
  float cx0 = floorf(cx), cy0 = floorf(cyv);
  float u = cx - cx0, v = cyv - cy0;
  float cx1 = fminf(cx0 + 1.0f, 2047.0f);
  float cy1 = fminf(cy0 + 1.0f, 2047.0f);

  const float cxc = (c & 1) ? cx1 : cx0;
  const float cyc = (c & 2) ? cy1 : cy0;
  const float wc = ((c & 1) ? u : 1.0f - u) * ((c & 2) ? v : 1.0f - v);

  const float K = 1.0f / 2048.0f;
  const float gx = (cxc + 0.5f) * K;
  const float gy = (cyc + 0.5f) * K;

  unsigned fw[16];

  #pragma unroll
  for (int lidx = 0; lidx < 16; ++lidx) {
    const int l = (lidx < 4) ? (12 + lidx) : (lidx - 4);
    const float scale   = P.lv[l].scale;
    const unsigned res  = P.lv[l].res;
    const unsigned size = P.lv[l].size;
    const unsigned off  = P.lv[l].offset;
    const bool hashed = (res * res) > size;

    float px = fmaf(gx, scale, 0.5f);
    float pgx = floorf(px);
    float frx = px - pgx;
    unsigned ux = (unsigned)pgx;

    float py = fmaf(gy, scale, 0.5f);
    float pgy = floorf(py);
    float fry = py - pgy;
    unsigned uy = (unsigned)pgy;

    unsigned i00, i01, i10, i11;
    if (hashed) {
      const unsigned m = size - 1u;
      unsigned hy0 = uy * PRIME_Y;
      unsigned hy1 = hy0 + PRIME_Y;
      i00 = (ux ^ hy0) & m;
      i01 = (ux ^ hy1) & m;
      i10 = ((ux + 1u) ^ hy0) & m;
      i11 = ((ux + 1u) ^ hy1) & m;
    } else {
      unsigned b0 = uy * res, b1 = b0 + res;
      unsigned q00 = ux + b0,      q01 = ux + b1;
      unsigned q10 = ux + 1u + b0, q11 = ux + 1u + b1;
      i00 = q00 >= size ? q00 - size : q00;
      i01 = q01 >= size ? q01 - size : q01;
      i10 = q10 >= size ? q10 - size : q10;
      i11 = q11 >= size ? q11 - size : q11;
    }

    F2 t00, t01, t10, t11;
    if (TBF == 1) {
      const unsigned* tb = tbf16 + off;
      t00 = bf2unpack(tb[i00]);
      t01 = bf2unpack(tb[i01]);
      t10 = bf2unpack(tb[i10]);
      t11 = bf2unpack(tb[i11]);
    } else {
      const F2* tabp = table + off;
      t00 = tabp[i00]; t01 = tabp[i01]; t10 = tabp[i10]; t11 = tabp[i11];
    }

    float wx0 = 1.0f - frx, wx1 = frx;
    float wy0 = 1.0f - fry, wy1 = fry;
    float w00 = wx0 * wy0, w01 = wx0 * wy1, w10 = wx1 * wy0, w11 = wx1 * wy1;
    float fx = w00 * t00.x + w01 * t01.x + w10 * t10.x + w11 * t11.x;
    float fy = w00 * t00.y + w01 * t01.y + w10 * t10.y + w11 * t11.y;
    fw[l] = bf2pack(fx, fy);
  }

  *(uint4*)(sFH + L * 80 +  0) = make_uint4(fw[0],  fw[1],  fw[2],  fw[3]);
  *(uint4*)(sFH + L * 80 + 16) = make_uint4(fw[4],  fw[5],  fw[6],  fw[7]);
  *(uint4*)(sFH + L * 80 + 32) = make_uint4(fw[8],  fw[9],  fw[10], fw[11]);
  *(uint4*)(sFH + L * 80 + 48) = make_uint4(fw[12], fw[13], fw[14], fw[15]);

  __syncthreads();

  short8 afr[4], bfr[4];
  #pragma unroll
  for (int b = 0; b < 4; ++b)
    bfr[b] = *(const short8*)(sFH + (16 * b + r16) * 80 + g * 16);
  #pragma unroll
  for (int a = 0; a < 4; ++a)
    afr[a] = *(const short8*)(smem + (16 * a + r16) * 80 + g * 16);

  f32x4 acc[4][4];
  #pragma unroll
  for (int a = 0; a < 4; ++a)
    #pragma unroll
    for (int b = 0; b < 4; ++b)
      acc[a][b] = (f32x4){0.f, 0.f, 0.f, 0.f};

  #pragma unroll
  for (int a = 0; a < 4; ++a)
    #pragma unroll
    for (int b = 0; b < 4; ++b)
      acc[a][b] = __builtin_amdgcn_mfma_f32_16x16x32_bf16(
          afr[a], bfr[b], acc[a][b], 0, 0, 0);

  #pragma unroll
  for (int a = 0; a < 4; ++a)
    #pragma unroll
    for (int b = 0; b < 4; ++b) {
      f32x4 h = acc[a][b];
      float h0 = fmaxf(h.x, 0.f), h1 = fmaxf(h.y, 0.f);
      float h2 = fmaxf(h.z, 0.f), h3 = fmaxf(h.w, 0.f);
      *(uint2*)(sFH + (16 * b + r16) * 128 +
                ((a * 32 + g * 8) ^ ((r16 & 7) << 4))) =
          make_uint2(bf2pack(h0, h1), bf2pack(h2, h3));
    }

  f32x4 oacc[4];
  #pragma unroll
  for (int b = 0; b < 4; ++b) oacc[b] = (f32x4){0.f, 0.f, 0.f, 0.f};

  #pragma unroll
  for (int ks = 0; ks < 2; ++ks) {
    short8 a2 = *(const short8*)(smem + 5120 + r16 * 128 +
                                 ((ks * 64 + g * 16) ^ ((r16 & 7) << 4)));
    #pragma unroll
    for (int b = 0; b < 4; ++b) {
      short8 b2 = *(const short8*)(sFH + (16 * b + r16) * 128 +
                                   ((ks * 64 + g * 16) ^ ((r16 & 7) << 4)));
      oacc[b] = __builtin_amdgcn_mfma_f32_16x16x32_bf16(a2, b2, oacc[b], 0, 0, 0);
    }
  }

  #pragma unroll
  for (int b = 0; b < 4; ++b) {
    float wcm = __shfl(wc, 16 * b + r16, 64);
    float v0 = oacc[b].x * wcm;
    float v1 = oacc[b].y * wcm;
    float v2 = oacc[b].z * wcm;
    float v3 = oacc[b].w * wcm;
    v0 += __shfl_xor(v0, 1, 64); v0 += __shfl_xor(v0, 2, 64);
    v1 += __shfl_xor(v1, 1, 64); v1 += __shfl_xor(v1, 2, 64);
    v2 += __shfl_xor(v2, 1, 64); v2 += __shfl_xor(v2, 2, 64);
    v3 += __shfl_xor(v3, 1, 64); v3 += __shfl_xor(v3, 2, 64);
    if ((L & 3) == 0 && g < 2) {
      int pt = blockIdx.x * 64 + w * 16 + 4 * b + (r16 >> 2);
      *(f32x4*)(out + (size_t)pt * 8 + 4 * g) = (f32x4){v0, v1, v2, v3};
    }
  }
}

extern "C" void kernel_launch(void* const* d_in, const int* in_sizes, int n_in,
                              void* d_out, int out_size, void* d_ws, size_t ws_size,
                              hipStream_t stream) {
  EncParams P;
  double b = exp2(log2(2048.0 / 16.0) / 15.0);
  unsigned off = 0;
  for (int l = 0; l < 16; ++l) {
    double s = 16.0 * pow(b, (double)l) - 1.0;
    int r = (int)ceil(s) + 1;
    unsigned p = (unsigned)(r * r);
    if (p > 524288u) p = 524288u;
    p = (p + 7u) / 8u * 8u;
    P.lv[l].scale = (float)s;
    P.lv[l].res = (unsigned)r;
    P.lv[l].size = p;
    P.lv[l].offset = off;
    off += p;
  }
  const int total_params = (int)off;

  int hstart = 16;
  for (int l = 0; l < 16; ++l) {
    unsigned long long rr = (unsigned long long)P.lv[l].res * P.lv[l].res;
    if (rr > P.lv[l].size) { hstart = l; break; }
  }
  const unsigned denseTotal = (hstart < 16) ? P.lv[hstart].offset
                                            : (unsigned)total_params;
  const size_t quadBytes = (size_t)denseTotal * 16;
  const size_t hashBytes = (size_t)((unsigned)total_params - denseTotal) * 4;
  const size_t packBytes = (size_t)total_params * 4;

  const int N = in_sizes[0] / 2;  // xy is [N,2]
  const F2* xy = (const F2*)d_in[0];
  const F2* table = (const F2*)d_in[1];
  const float* w0g = (const float*)d_in[2];
  const float* w1g = (const float*)d_in[3];
  const int* bp = (const int*)d_in[4];
  float* outp = (float*)d_out;

  if (hstart == 12 && (N & 127) == 0 && ws_size >= quadBytes + hashBytes) {
    uint4* quad = (uint4*)d_ws;
    unsigned* hp = (unsigned*)((char*)d_ws + quadBytes);
    prep3<<<(total_params + 255) / 256, 256, 0, stream>>>(
        table, quad, hp, P, denseTotal, (unsigned)total_params);
    plane_fwd1<<<N / 128, 256, 0, stream>>>(xy, quad, hp, w0g, w1g, bp,
                                            outp, P);
  } else if (ws_size >= packBytes) {
    unsigned* tbf = (unsigned*)d_ws;
    cvt_table<<<(total_params + 255) / 256, 256, 0, stream>>>(table, tbf,
                                                              total_params);
    plane_fwd<1><<<N / 64, 256, 0, stream>>>(xy, table, tbf, w0g, w1g, bp,
                                             outp, P);
  } else {
    plane_fwd<0><<<N / 64, 256, 0, stream>>>(xy, table, nullptr, w0g, w1g, bp,
                                             outp, P);
  }
}